// Round 3
// baseline (248.125 us; speedup 1.0000x reference)
//
#include <hip/hip_runtime.h>
#include <hip/hip_bf16.h>

// Problem constants
#define HID 512
#define SEQ 2048
#define NBATCH 4
#define NHEAD 8
#define NG 32            // NBATCH*NHEAD heads after (buggy-but-faithful) reshape
#define HD 64
#define MROWS 8192       // NBATCH*SEQ
#define LDP 72           // padded LDS row stride (elements) -> 144B, breaks 128B-stride conflicts

typedef __bf16 bf16x8 __attribute__((ext_vector_type(8)));
typedef float f32x4 __attribute__((ext_vector_type(4)));

#define MFMA(a, b, c) __builtin_amdgcn_mfma_f32_16x16x32_bf16((a), (b), (c), 0, 0, 0)

// ---------------------------------------------------------------------------
// GEMM: C_bf16[M x 512] = bf16( X_f32 @ W^T + bias ),  W is [n][k] row-major
// grid (M/64, 512/64), block 256 (4 waves); wave computes 16x64 of C.
// ---------------------------------------------------------------------------
__global__ __launch_bounds__(256) void gemm_qkv(const float* __restrict__ X,
                                                const float* __restrict__ W,
                                                const float* __restrict__ bias,
                                                __hip_bfloat16* __restrict__ C) {
    __shared__ __hip_bfloat16 Xs[64][LDP];
    __shared__ __hip_bfloat16 Ws[64][LDP];
    const int tid = threadIdx.x;
    const int w = tid >> 6, l = tid & 63;
    const int row0 = blockIdx.x * 64, col0 = blockIdx.y * 64;

    f32x4 acc[4] = {};
    for (int kt = 0; kt < 8; ++kt) {
        __syncthreads();
        // stage X tile (64x64 f32 -> bf16)
        for (int c = tid; c < 1024; c += 256) {
            int r = c >> 4, col = (c & 15) * 4;
            float4 v = *(const float4*)(X + (size_t)(row0 + r) * HID + kt * 64 + col);
            union { __hip_bfloat16 h[4]; uint2 u; } p;
            p.h[0] = __float2bfloat16(v.x); p.h[1] = __float2bfloat16(v.y);
            p.h[2] = __float2bfloat16(v.z); p.h[3] = __float2bfloat16(v.w);
            *(uint2*)&Xs[r][col] = p.u;
        }
        // stage W tile rows n=col0.., cols k=kt*64..
        for (int c = tid; c < 1024; c += 256) {
            int r = c >> 4, col = (c & 15) * 4;
            float4 v = *(const float4*)(W + (size_t)(col0 + r) * HID + kt * 64 + col);
            union { __hip_bfloat16 h[4]; uint2 u; } p;
            p.h[0] = __float2bfloat16(v.x); p.h[1] = __float2bfloat16(v.y);
            p.h[2] = __float2bfloat16(v.z); p.h[3] = __float2bfloat16(v.w);
            *(uint2*)&Ws[r][col] = p.u;
        }
        __syncthreads();
        for (int dk = 0; dk < 2; ++dk) {
            bf16x8 a = *(const bf16x8*)&Xs[w * 16 + (l & 15)][dk * 32 + 8 * (l >> 4)];
            for (int nt = 0; nt < 4; ++nt) {
                bf16x8 b = *(const bf16x8*)&Ws[nt * 16 + (l & 15)][dk * 32 + 8 * (l >> 4)];
                acc[nt] = MFMA(a, b, acc[nt]);
            }
        }
    }
    // epilogue: D[m][n] lane map: n = l&15, m = 4*(l>>4)+jj
    for (int nt = 0; nt < 4; ++nt) {
        int n = col0 + nt * 16 + (l & 15);
        float bv = bias[n];
        for (int jj = 0; jj < 4; ++jj) {
            int r = row0 + w * 16 + 4 * (l >> 4) + jj;
            C[(size_t)r * HID + n] = __float2bfloat16(acc[nt][jj] + bv);
        }
    }
}

// ---------------------------------------------------------------------------
// GEMM: out_f32[M x 512] = X2_bf16 @ W^T + bias
// ---------------------------------------------------------------------------
__global__ __launch_bounds__(256) void gemm_out(const __hip_bfloat16* __restrict__ X,
                                                const float* __restrict__ W,
                                                const float* __restrict__ bias,
                                                float* __restrict__ out) {
    __shared__ __hip_bfloat16 Xs[64][LDP];
    __shared__ __hip_bfloat16 Ws[64][LDP];
    const int tid = threadIdx.x;
    const int w = tid >> 6, l = tid & 63;
    const int row0 = blockIdx.x * 64, col0 = blockIdx.y * 64;

    f32x4 acc[4] = {};
    for (int kt = 0; kt < 8; ++kt) {
        __syncthreads();
        for (int c = tid; c < 512; c += 256) {      // X already bf16: 16B chunks
            int r = c >> 3, col = (c & 7) * 8;
            *(uint4*)&Xs[r][col] = *(const uint4*)(X + (size_t)(row0 + r) * HID + kt * 64 + col);
        }
        for (int c = tid; c < 1024; c += 256) {
            int r = c >> 4, col = (c & 15) * 4;
            float4 v = *(const float4*)(W + (size_t)(col0 + r) * HID + kt * 64 + col);
            union { __hip_bfloat16 h[4]; uint2 u; } p;
            p.h[0] = __float2bfloat16(v.x); p.h[1] = __float2bfloat16(v.y);
            p.h[2] = __float2bfloat16(v.z); p.h[3] = __float2bfloat16(v.w);
            *(uint2*)&Ws[r][col] = p.u;
        }
        __syncthreads();
        for (int dk = 0; dk < 2; ++dk) {
            bf16x8 a = *(const bf16x8*)&Xs[w * 16 + (l & 15)][dk * 32 + 8 * (l >> 4)];
            for (int nt = 0; nt < 4; ++nt) {
                bf16x8 b = *(const bf16x8*)&Ws[nt * 16 + (l & 15)][dk * 32 + 8 * (l >> 4)];
                acc[nt] = MFMA(a, b, acc[nt]);
            }
        }
    }
    for (int nt = 0; nt < 4; ++nt) {
        int n = col0 + nt * 16 + (l & 15);
        float bv = bias[n];
        for (int jj = 0; jj < 4; ++jj) {
            int r = row0 + w * 16 + 4 * (l >> 4) + jj;
            out[(size_t)r * HID + n] = acc[nt][jj] + bv;
        }
    }
}

// ---------------------------------------------------------------------------
// Attention: per block = one head g, 64 q-rows. Writes WV^T[g][d][i] so the
// final reshape is a free flat view. Softmax without max-subtraction (scores
// are tiny: |s| < ~1 after 1/sqrt(512) scaling), masked keys get p=0.
// ---------------------------------------------------------------------------
__global__ __launch_bounds__(256) void attn(const __hip_bfloat16* __restrict__ qg,
                                            const __hip_bfloat16* __restrict__ kg,
                                            const __hip_bfloat16* __restrict__ vg,
                                            const int* __restrict__ mask,
                                            __hip_bfloat16* __restrict__ wvt) {
    __shared__ __hip_bfloat16 Qs[64][LDP];
    __shared__ __hip_bfloat16 Ks[64][LDP];
    __shared__ __hip_bfloat16 VT[64][LDP];
    __shared__ __hip_bfloat16 Ps[64][LDP];
    __shared__ float lpart[4][64];
    __shared__ float linv[64];
    __shared__ int msk[64];

    const int tid = threadIdx.x;
    const int w = tid >> 6, l = tid & 63;
    const int g = blockIdx.x >> 5, qt = blockIdx.x & 31;
    const size_t hb = (size_t)g * (SEQ * HD);
    const float SCALE = 0.04419417382415922f;   // 1/sqrt(512)

    // stage Q tile once (rows qt*64..)
    for (int c = tid; c < 512; c += 256) {
        int r = c >> 3, col = (c & 7) * 8;
        *(uint4*)&Qs[r][col] = *(const uint4*)(qg + hb + (size_t)(qt * 64 + r) * HD + col);
    }

    f32x4 acc[4] = {};
    float lacc = 0.f;

    for (int kt = 0; kt < 32; ++kt) {
        __syncthreads();   // protect restage vs previous iteration's reads
        // stage K tile
        for (int c = tid; c < 512; c += 256) {
            int r = c >> 3, col = (c & 7) * 8;
            *(uint4*)&Ks[r][col] = *(const uint4*)(kg + hb + (size_t)(kt * 64 + r) * HD + col);
        }
        // stage V transposed: VT[d][k_local]
        for (int c = tid; c < 512; c += 256) {
            int r = c >> 3, d0 = (c & 7) * 8;
            union { uint4 u; __hip_bfloat16 h[8]; } vv;
            vv.u = *(const uint4*)(vg + hb + (size_t)(kt * 64 + r) * HD + d0);
            for (int j = 0; j < 8; ++j) VT[d0 + j][r] = vv.h[j];
        }
        if (tid < 64) msk[tid] = mask[kt * 64 + tid];
        __syncthreads();

        // S = Q K^T for this wave's 16 q-rows (16x64)
        f32x4 sacc[4] = {};
        for (int dk = 0; dk < 2; ++dk) {
            bf16x8 a = *(const bf16x8*)&Qs[w * 16 + (l & 15)][dk * 32 + 8 * (l >> 4)];
            for (int nt = 0; nt < 4; ++nt) {
                bf16x8 b = *(const bf16x8*)&Ks[nt * 16 + (l & 15)][dk * 32 + 8 * (l >> 4)];
                sacc[nt] = MFMA(a, b, sacc[nt]);
            }
        }
        // mask + exp, write P tile (wave-local rows)
        for (int nt = 0; nt < 4; ++nt) {
            int kc = nt * 16 + (l & 15);
            bool mok = (msk[kc] != 0);
            for (int jj = 0; jj < 4; ++jj) {
                float p = mok ? __expf(sacc[nt][jj] * SCALE) : 0.f;
                Ps[w * 16 + 4 * (l >> 4) + jj][kc] = __float2bfloat16(p);
            }
        }
        __syncthreads();

        // row sums (each wave reads only its own 16 rows)
        {
            int q = w * 16 + (l & 15), part = l >> 4;
            union { uint4 u; __hip_bfloat16 h[8]; } p0, p1;
            p0.u = *(const uint4*)&Ps[q][part * 16];
            p1.u = *(const uint4*)&Ps[q][part * 16 + 8];
            float s = 0.f;
            for (int j = 0; j < 8; ++j)
                s += __bfloat162float(p0.h[j]) + __bfloat162float(p1.h[j]);
            lacc += s;
        }
        // acc += P @ V   (B operand from transposed V -> contiguous reads)
        for (int kk = 0; kk < 2; ++kk) {
            bf16x8 a = *(const bf16x8*)&Ps[w * 16 + (l & 15)][kk * 32 + 8 * (l >> 4)];
            for (int dt = 0; dt < 4; ++dt) {
                bf16x8 b = *(const bf16x8*)&VT[dt * 16 + (l & 15)][kk * 32 + 8 * (l >> 4)];
                acc[dt] = MFMA(a, b, acc[dt]);
            }
        }
    }

    // finalize 1/l
    {
        int q = w * 16 + (l & 15), part = l >> 4;
        lpart[part][q] = lacc;
    }
    __syncthreads();
    if (tid < 64)
        linv[tid] = 1.f / (lpart[0][tid] + lpart[1][tid] + lpart[2][tid] + lpart[3][tid]);
    __syncthreads();

    // write WV^T[g][d][i]: lane has q = w*16+4*(l>>4)+jj, d = dt*16+(l&15)
    const int qb4 = w * 16 + 4 * (l >> 4);
    const int ibase = qt * 64 + qb4;
    for (int dt = 0; dt < 4; ++dt) {
        int d = dt * 16 + (l & 15);
        union { __hip_bfloat16 h[4]; uint2 u; } o;
        for (int jj = 0; jj < 4; ++jj)
            o.h[jj] = __float2bfloat16(acc[dt][jj] * linv[qb4 + jj]);
        *(uint2*)(wvt + (size_t)g * (HD * SEQ) + (size_t)d * SEQ + ibase) = o.u;
    }
}

// ---------------------------------------------------------------------------
extern "C" void kernel_launch(void* const* d_in, const int* in_sizes, int n_in,
                              void* d_out, int out_size, void* d_ws, size_t ws_size,
                              hipStream_t stream) {
    const float* lstm = (const float*)d_in[0];
    const int* mask = (const int*)d_in[1];
    const float* Wq = (const float*)d_in[2]; const float* bq = (const float*)d_in[3];
    const float* Wk = (const float*)d_in[4]; const float* bk = (const float*)d_in[5];
    const float* Wv = (const float*)d_in[6]; const float* bv = (const float*)d_in[7];
    const float* Wo = (const float*)d_in[8]; const float* bo = (const float*)d_in[9];
    float* out = (float*)d_out;

    __hip_bfloat16* qb  = (__hip_bfloat16*)d_ws;
    __hip_bfloat16* kb  = qb + (size_t)MROWS * HID;
    __hip_bfloat16* vb  = kb + (size_t)MROWS * HID;
    __hip_bfloat16* wvt = vb + (size_t)MROWS * HID;

    dim3 gg(MROWS / 64, HID / 64), bb(256);
    gemm_qkv<<<gg, bb, 0, stream>>>(lstm, Wq, bq, qb);
    gemm_qkv<<<gg, bb, 0, stream>>>(lstm, Wk, bk, kb);
    gemm_qkv<<<gg, bb, 0, stream>>>(lstm, Wv, bv, vb);
    attn<<<dim3(NG * (SEQ / 64)), bb, 0, stream>>>(qb, kb, vb, mask, wvt);
    gemm_out<<<gg, bb, 0, stream>>>(wvt, Wo, bo, out);
}

// Round 7
// 170.851 us; speedup vs baseline: 1.4523x; 1.4523x over previous
//
#include <hip/hip_runtime.h>
#include <hip/hip_bf16.h>

// Problem constants
#define HID 512
#define SEQ 2048
#define NG 32            // (B*NUM_HEADS) after the faithful-to-source flat reshape
#define HD 64
#define MROWS 8192       // B*SEQ
#define LDP 72           // padded LDS row stride (elems) = 144B; all hot patterns <=2-way

typedef __bf16 bf16x8 __attribute__((ext_vector_type(8)));
typedef float f32x4 __attribute__((ext_vector_type(4)));

#define MFMA(a, b, c) __builtin_amdgcn_mfma_f32_16x16x32_bf16((a), (b), (c), 0, 0, 0)

// ---------------------------------------------------------------------------
// prep: f32 -> bf16 vectorized converts
// ---------------------------------------------------------------------------
__global__ __launch_bounds__(256) void conv_x(const float* __restrict__ src,
                                              __hip_bfloat16* __restrict__ dst, int n4) {
    int stride = gridDim.x * 256;
    for (int i = blockIdx.x * 256 + threadIdx.x; i < n4; i += stride) {
        float4 v = *(const float4*)(src + (size_t)i * 4);
        union { __hip_bfloat16 h[4]; uint2 u; } p;
        p.h[0] = __float2bfloat16(v.x); p.h[1] = __float2bfloat16(v.y);
        p.h[2] = __float2bfloat16(v.z); p.h[3] = __float2bfloat16(v.w);
        *(uint2*)(dst + (size_t)i * 4) = p.u;
    }
}

__global__ __launch_bounds__(256) void conv_w(const float* __restrict__ a,
                                              const float* __restrict__ b,
                                              const float* __restrict__ c,
                                              const float* __restrict__ d,
                                              __hip_bfloat16* __restrict__ out) {
    int which = blockIdx.y;
    const float* s = which == 0 ? a : (which == 1 ? b : (which == 2 ? c : d));
    __hip_bfloat16* o = out + (size_t)which * (HID * HID);
    int i = blockIdx.x * 256 + threadIdx.x;   // 65536 threads, 65536 float4 per W
    float4 v = *(const float4*)(s + (size_t)i * 4);
    union { __hip_bfloat16 h[4]; uint2 u; } p;
    p.h[0] = __float2bfloat16(v.x); p.h[1] = __float2bfloat16(v.y);
    p.h[2] = __float2bfloat16(v.z); p.h[3] = __float2bfloat16(v.w);
    *(uint2*)(o + (size_t)i * 4) = p.u;
}

// ---------------------------------------------------------------------------
// Fused QKV GEMM: {q,k}[M x 512] row-major bf16; v written TRANSPOSED per
// head: vT[g][d][i] (g=m>>8, i=(m&255)*8+(n>>6), d=n&63) so attn stages V
// with coalesced loads + conflict-free LDS writes.
// grid (128, 8), block 256 (4 waves); wave computes 16x64 per output.
// ---------------------------------------------------------------------------
__global__ __launch_bounds__(256) void gemm_qkv_fused(
        const __hip_bfloat16* __restrict__ Xb,
        const __hip_bfloat16* __restrict__ Wqb, const __hip_bfloat16* __restrict__ Wkb,
        const __hip_bfloat16* __restrict__ Wvb,
        const float* __restrict__ bq, const float* __restrict__ bk, const float* __restrict__ bv,
        __hip_bfloat16* __restrict__ qout, __hip_bfloat16* __restrict__ kout,
        __hip_bfloat16* __restrict__ vT) {
    __shared__ __hip_bfloat16 Xs[64][LDP];
    __shared__ __hip_bfloat16 Wqs[64][LDP];
    __shared__ __hip_bfloat16 Wks[64][LDP];
    __shared__ __hip_bfloat16 Wvs[64][LDP];
    const int tid = threadIdx.x;
    const int w = tid >> 6, l = tid & 63;
    const int row0 = blockIdx.x * 64, col0 = blockIdx.y * 64;

    f32x4 aq[4] = {}, ak[4] = {}, av[4] = {};
    for (int kt = 0; kt < 8; ++kt) {
        __syncthreads();
        for (int c = tid; c < 512; c += 256) {
            int r = c >> 3, col = (c & 7) * 8;
            size_t go = (size_t)kt * 64 + col;
            *(uint4*)&Xs[r][col]  = *(const uint4*)(Xb  + (size_t)(row0 + r) * HID + go);
            *(uint4*)&Wqs[r][col] = *(const uint4*)(Wqb + (size_t)(col0 + r) * HID + go);
            *(uint4*)&Wks[r][col] = *(const uint4*)(Wkb + (size_t)(col0 + r) * HID + go);
            *(uint4*)&Wvs[r][col] = *(const uint4*)(Wvb + (size_t)(col0 + r) * HID + go);
        }
        __syncthreads();
        for (int dk = 0; dk < 2; ++dk) {
            bf16x8 a = *(const bf16x8*)&Xs[w * 16 + (l & 15)][dk * 32 + 8 * (l >> 4)];
            for (int nt = 0; nt < 4; ++nt) {
                int rr = nt * 16 + (l & 15), cc = dk * 32 + 8 * (l >> 4);
                aq[nt] = MFMA(a, *(const bf16x8*)&Wqs[rr][cc], aq[nt]);
                ak[nt] = MFMA(a, *(const bf16x8*)&Wks[rr][cc], ak[nt]);
                av[nt] = MFMA(a, *(const bf16x8*)&Wvs[rr][cc], av[nt]);
            }
        }
    }
    // epilogue
    const int g = row0 >> 8;
    const int rbase = (row0 & 255) + w * 16 + 4 * (l >> 4);
    for (int nt = 0; nt < 4; ++nt) {
        int n = col0 + nt * 16 + (l & 15);
        float bqv = bq[n], bkv = bk[n], bvv = bv[n];
        int d = n & 63;   // col0 is a multiple of 64
        for (int jj = 0; jj < 4; ++jj) {
            int r = row0 + w * 16 + 4 * (l >> 4) + jj;
            qout[(size_t)r * HID + n] = __float2bfloat16(aq[nt][jj] + bqv);
            kout[(size_t)r * HID + n] = __float2bfloat16(ak[nt][jj] + bkv);
            vT[(size_t)g * (HD * SEQ) + (size_t)d * SEQ + (rbase + jj) * 8 + blockIdx.y] =
                __float2bfloat16(av[nt][jj] + bvv);
        }
    }
}

// ---------------------------------------------------------------------------
// GEMM: out_f32[M x 512] = X_bf16 @ Wo_bf16^T + bo
// ---------------------------------------------------------------------------
__global__ __launch_bounds__(256) void gemm_out(const __hip_bfloat16* __restrict__ X,
                                                const __hip_bfloat16* __restrict__ W,
                                                const float* __restrict__ bias,
                                                float* __restrict__ out) {
    __shared__ __hip_bfloat16 Xs[64][LDP];
    __shared__ __hip_bfloat16 Ws[64][LDP];
    const int tid = threadIdx.x;
    const int w = tid >> 6, l = tid & 63;
    const int row0 = blockIdx.x * 64, col0 = blockIdx.y * 64;

    f32x4 acc[4] = {};
    for (int kt = 0; kt < 8; ++kt) {
        __syncthreads();
        for (int c = tid; c < 512; c += 256) {
            int r = c >> 3, col = (c & 7) * 8;
            *(uint4*)&Xs[r][col] = *(const uint4*)(X + (size_t)(row0 + r) * HID + kt * 64 + col);
            *(uint4*)&Ws[r][col] = *(const uint4*)(W + (size_t)(col0 + r) * HID + kt * 64 + col);
        }
        __syncthreads();
        for (int dk = 0; dk < 2; ++dk) {
            bf16x8 a = *(const bf16x8*)&Xs[w * 16 + (l & 15)][dk * 32 + 8 * (l >> 4)];
            for (int nt = 0; nt < 4; ++nt) {
                bf16x8 b = *(const bf16x8*)&Ws[nt * 16 + (l & 15)][dk * 32 + 8 * (l >> 4)];
                acc[nt] = MFMA(a, b, acc[nt]);
            }
        }
    }
    for (int nt = 0; nt < 4; ++nt) {
        int n = col0 + nt * 16 + (l & 15);
        float bv = bias[n];
        for (int jj = 0; jj < 4; ++jj) {
            int r = row0 + w * 16 + 4 * (l >> 4) + jj;
            out[(size_t)r * HID + n] = acc[nt][jj] + bv;
        }
    }
}

// ---------------------------------------------------------------------------
// Attention. Block = (head g, 64 q-rows). V comes in pre-transposed (vT), so
// both K and V stage with coalesced uint4 loads + b128 LDS writes.
// Barrier after Ps writes: the Ps stores are scalar bf16, the reads are
// uint4/bf16x8 type-punned — without a full LDS fence the compiler may
// reorder across the (TBAA-invisible) dependence. Round-3 structure, proven.
// ---------------------------------------------------------------------------
__global__ __launch_bounds__(256) void attn(const __hip_bfloat16* __restrict__ qg,
                                            const __hip_bfloat16* __restrict__ kg,
                                            const __hip_bfloat16* __restrict__ vT,
                                            const int* __restrict__ mask,
                                            __hip_bfloat16* __restrict__ wvt) {
    __shared__ __hip_bfloat16 Qs[64][LDP];
    __shared__ __hip_bfloat16 Ks[64][LDP];
    __shared__ __hip_bfloat16 VTs[64][LDP];
    __shared__ __hip_bfloat16 Ps[64][LDP];
    __shared__ float lpart[4][64];
    __shared__ float linv[64];
    __shared__ int msk[64];

    const int tid = threadIdx.x;
    const int w = tid >> 6, l = tid & 63;
    // XCD-chunked swizzle: 1024 blocks % 8 == 0 -> bijective
    const int bid = (blockIdx.x & 7) * 128 + (blockIdx.x >> 3);
    const int g = bid >> 5, qt = bid & 31;
    const size_t hb = (size_t)g * (SEQ * HD);
    const float SCALE = 0.04419417382415922f;   // 1/sqrt(512)

    for (int c = tid; c < 512; c += 256) {
        int r = c >> 3, col = (c & 7) * 8;
        *(uint4*)&Qs[r][col] = *(const uint4*)(qg + hb + (size_t)(qt * 64 + r) * HD + col);
    }

    f32x4 acc[4] = {};
    float lacc = 0.f;

    for (int kt = 0; kt < 32; ++kt) {
        __syncthreads();   // previous iteration's reads done before restage
        for (int c = tid; c < 512; c += 256) {
            int r = c >> 3, col = (c & 7) * 8;
            *(uint4*)&Ks[r][col]  = *(const uint4*)(kg + hb + (size_t)(kt * 64 + r) * HD + col);
            // vT[g][d=r][i=kt*64+col ..]: coalesced 16B, conflict-free b128 LDS write
            *(uint4*)&VTs[r][col] = *(const uint4*)(vT + hb + (size_t)r * SEQ + kt * 64 + col);
        }
        if (tid < 64) msk[tid] = mask[kt * 64 + tid];
        __syncthreads();

        // S = Q K^T (wave's 16 q-rows x 64 keys)
        f32x4 sacc[4] = {};
        for (int dk = 0; dk < 2; ++dk) {
            bf16x8 a = *(const bf16x8*)&Qs[w * 16 + (l & 15)][dk * 32 + 8 * (l >> 4)];
            for (int nt = 0; nt < 4; ++nt) {
                bf16x8 b = *(const bf16x8*)&Ks[nt * 16 + (l & 15)][dk * 32 + 8 * (l >> 4)];
                sacc[nt] = MFMA(a, b, sacc[nt]);
            }
        }
        // mask + exp -> P
        for (int nt = 0; nt < 4; ++nt) {
            int kc = nt * 16 + (l & 15);
            bool mok = (msk[kc] != 0);
            for (int jj = 0; jj < 4; ++jj) {
                float p = mok ? __expf(sacc[nt][jj] * SCALE) : 0.f;
                Ps[w * 16 + 4 * (l >> 4) + jj][kc] = __float2bfloat16(p);
            }
        }
        __syncthreads();   // full LDS fence: order Ps stores before punned reads

        // row sums (each wave reads its own 16 rows)
        {
            int q = w * 16 + (l & 15), part = l >> 4;
            union { uint4 u; __hip_bfloat16 h[8]; } p0, p1;
            p0.u = *(const uint4*)&Ps[q][part * 16];
            p1.u = *(const uint4*)&Ps[q][part * 16 + 8];
            float s = 0.f;
            for (int j = 0; j < 8; ++j)
                s += __bfloat162float(p0.h[j]) + __bfloat162float(p1.h[j]);
            lacc += s;
        }
        // acc += P @ V  (B-operand rows are d, cols are k: VTs[d][k_local])
        for (int kk = 0; kk < 2; ++kk) {
            bf16x8 a = *(const bf16x8*)&Ps[w * 16 + (l & 15)][kk * 32 + 8 * (l >> 4)];
            for (int dt = 0; dt < 4; ++dt) {
                bf16x8 b = *(const bf16x8*)&VTs[dt * 16 + (l & 15)][kk * 32 + 8 * (l >> 4)];
                acc[dt] = MFMA(a, b, acc[dt]);
            }
        }
    }

    {
        int q = w * 16 + (l & 15), part = l >> 4;
        lpart[part][q] = lacc;
    }
    __syncthreads();
    if (tid < 64)
        linv[tid] = 1.f / (lpart[0][tid] + lpart[1][tid] + lpart[2][tid] + lpart[3][tid]);
    __syncthreads();

    const int qb4 = w * 16 + 4 * (l >> 4);
    const int ibase = qt * 64 + qb4;
    for (int dt = 0; dt < 4; ++dt) {
        int d = dt * 16 + (l & 15);
        union { __hip_bfloat16 h[4]; uint2 u; } o;
        for (int jj = 0; jj < 4; ++jj)
            o.h[jj] = __float2bfloat16(acc[dt][jj] * linv[qb4 + jj]);
        *(uint2*)(wvt + (size_t)g * (HD * SEQ) + (size_t)d * SEQ + ibase) = o.u;
    }
}

// ---------------------------------------------------------------------------
// ws layout (26 MB peak — well under the round-3-proven 32 MB):
//   Xb [0,8MB) -> aliased by wvt after QKV GEMM; W bf16 [8,10MB);
//   qb [10,18MB); kb [18,26MB).
// vT lives in d_out's first 8 MB: dead before gemm_out, which then
// overwrites all of d_out. Legal scratch, deterministic every call.
// ---------------------------------------------------------------------------
extern "C" void kernel_launch(void* const* d_in, const int* in_sizes, int n_in,
                              void* d_out, int out_size, void* d_ws, size_t ws_size,
                              hipStream_t stream) {
    const float* lstm = (const float*)d_in[0];
    const int* mask = (const int*)d_in[1];
    const float* Wq = (const float*)d_in[2]; const float* bq = (const float*)d_in[3];
    const float* Wk = (const float*)d_in[4]; const float* bk = (const float*)d_in[5];
    const float* Wv = (const float*)d_in[6]; const float* bv = (const float*)d_in[7];
    const float* Wo = (const float*)d_in[8]; const float* bo = (const float*)d_in[9];
    float* out = (float*)d_out;

    const size_t NX = (size_t)MROWS * HID;    // 4M elems
    const size_t NW = (size_t)HID * HID;      // 256K elems
    __hip_bfloat16* Xb  = (__hip_bfloat16*)d_ws;            // 4M elems (8MB)
    __hip_bfloat16* Wqb = Xb + NX;                          // 256K
    __hip_bfloat16* Wkb = Wqb + NW;
    __hip_bfloat16* Wvb = Wkb + NW;
    __hip_bfloat16* Wob = Wvb + NW;
    __hip_bfloat16* qb  = Wob + NW;                         // 4M
    __hip_bfloat16* kb  = qb + NX;                          // 4M
    __hip_bfloat16* vT  = (__hip_bfloat16*)d_out;           // scratch in d_out[0,8MB)
    __hip_bfloat16* wvt = Xb;                               // alias: Xb dead after QKV GEMM

    conv_x<<<2048, 256, 0, stream>>>(lstm, Xb, (int)(NX / 4));
    conv_w<<<dim3(256, 4), 256, 0, stream>>>(Wq, Wk, Wv, Wo, Wqb);

    dim3 gg(MROWS / 64, HID / 64), bb(256);
    gemm_qkv_fused<<<gg, bb, 0, stream>>>(Xb, Wqb, Wkb, Wvb, bq, bk, bv, qb, kb, vT);
    attn<<<dim3(NG * (SEQ / 64)), bb, 0, stream>>>(qb, kb, vT, mask, wvt);
    gemm_out<<<gg, bb, 0, stream>>>(wvt, Wob, bo, out);
}

// Round 9
// 161.798 us; speedup vs baseline: 1.5335x; 1.0560x over previous
//
#include <hip/hip_runtime.h>
#include <hip/hip_bf16.h>

// Problem constants
#define HID 512
#define SEQ 2048
#define NG 32            // (B*NUM_HEADS) after the faithful-to-source flat reshape
#define HD 64
#define MROWS 8192       // B*SEQ
#define LDP 72           // padded LDS row stride (elems) = 144B
// 1/sqrt(512) * log2(e): folded into Q so softmax is exp2(s)
#define QSC 0.0637587178f

typedef __bf16 bf16x8 __attribute__((ext_vector_type(8)));
typedef float f32x4 __attribute__((ext_vector_type(4)));

#define MFMA(a, b, c) __builtin_amdgcn_mfma_f32_16x16x32_bf16((a), (b), (c), 0, 0, 0)

// ---------------------------------------------------------------------------
// prep: f32 -> bf16 vectorized converts
// ---------------------------------------------------------------------------
__global__ __launch_bounds__(256) void conv_x(const float* __restrict__ src,
                                              __hip_bfloat16* __restrict__ dst, int n4) {
    int stride = gridDim.x * 256;
    for (int i = blockIdx.x * 256 + threadIdx.x; i < n4; i += stride) {
        float4 v = *(const float4*)(src + (size_t)i * 4);
        union { __hip_bfloat16 h[4]; uint2 u; } p;
        p.h[0] = __float2bfloat16(v.x); p.h[1] = __float2bfloat16(v.y);
        p.h[2] = __float2bfloat16(v.z); p.h[3] = __float2bfloat16(v.w);
        *(uint2*)(dst + (size_t)i * 4) = p.u;
    }
}

__global__ __launch_bounds__(256) void conv_w(const float* __restrict__ a,
                                              const float* __restrict__ b,
                                              const float* __restrict__ c,
                                              const float* __restrict__ d,
                                              __hip_bfloat16* __restrict__ out) {
    int which = blockIdx.y;
    const float* s = which == 0 ? a : (which == 1 ? b : (which == 2 ? c : d));
    __hip_bfloat16* o = out + (size_t)which * (HID * HID);
    int i = blockIdx.x * 256 + threadIdx.x;   // 65536 float4 per W
    float4 v = *(const float4*)(s + (size_t)i * 4);
    union { __hip_bfloat16 h[4]; uint2 u; } p;
    p.h[0] = __float2bfloat16(v.x); p.h[1] = __float2bfloat16(v.y);
    p.h[2] = __float2bfloat16(v.z); p.h[3] = __float2bfloat16(v.w);
    *(uint2*)(o + (size_t)i * 4) = p.u;
}

// ---------------------------------------------------------------------------
// Fused QKV GEMM. q is pre-scaled by QSC (softmax scale folded in, exp2 form).
// v written transposed per head: vT[g][d][i].
// ---------------------------------------------------------------------------
__global__ __launch_bounds__(256) void gemm_qkv_fused(
        const __hip_bfloat16* __restrict__ Xb,
        const __hip_bfloat16* __restrict__ Wqb, const __hip_bfloat16* __restrict__ Wkb,
        const __hip_bfloat16* __restrict__ Wvb,
        const float* __restrict__ bq, const float* __restrict__ bk, const float* __restrict__ bv,
        __hip_bfloat16* __restrict__ qout, __hip_bfloat16* __restrict__ kout,
        __hip_bfloat16* __restrict__ vT) {
    __shared__ __hip_bfloat16 Xs[64][LDP];
    __shared__ __hip_bfloat16 Wqs[64][LDP];
    __shared__ __hip_bfloat16 Wks[64][LDP];
    __shared__ __hip_bfloat16 Wvs[64][LDP];
    const int tid = threadIdx.x;
    const int w = tid >> 6, l = tid & 63;
    const int row0 = blockIdx.x * 64, col0 = blockIdx.y * 64;

    f32x4 aq[4] = {}, ak[4] = {}, av[4] = {};
    for (int kt = 0; kt < 8; ++kt) {
        __syncthreads();
        for (int c = tid; c < 512; c += 256) {
            int r = c >> 3, col = (c & 7) * 8;
            size_t go = (size_t)kt * 64 + col;
            *(uint4*)&Xs[r][col]  = *(const uint4*)(Xb  + (size_t)(row0 + r) * HID + go);
            *(uint4*)&Wqs[r][col] = *(const uint4*)(Wqb + (size_t)(col0 + r) * HID + go);
            *(uint4*)&Wks[r][col] = *(const uint4*)(Wkb + (size_t)(col0 + r) * HID + go);
            *(uint4*)&Wvs[r][col] = *(const uint4*)(Wvb + (size_t)(col0 + r) * HID + go);
        }
        __syncthreads();
        for (int dk = 0; dk < 2; ++dk) {
            bf16x8 a = *(const bf16x8*)&Xs[w * 16 + (l & 15)][dk * 32 + 8 * (l >> 4)];
            for (int nt = 0; nt < 4; ++nt) {
                int rr = nt * 16 + (l & 15), cc = dk * 32 + 8 * (l >> 4);
                aq[nt] = MFMA(a, *(const bf16x8*)&Wqs[rr][cc], aq[nt]);
                ak[nt] = MFMA(a, *(const bf16x8*)&Wks[rr][cc], ak[nt]);
                av[nt] = MFMA(a, *(const bf16x8*)&Wvs[rr][cc], av[nt]);
            }
        }
    }
    // epilogue
    const int g = row0 >> 8;
    const int rbase = (row0 & 255) + w * 16 + 4 * (l >> 4);
    for (int nt = 0; nt < 4; ++nt) {
        int n = col0 + nt * 16 + (l & 15);
        float bqv = bq[n], bkv = bk[n], bvv = bv[n];
        int d = n & 63;   // col0 is a multiple of 64
        for (int jj = 0; jj < 4; ++jj) {
            int r = row0 + w * 16 + 4 * (l >> 4) + jj;
            qout[(size_t)r * HID + n] = __float2bfloat16((aq[nt][jj] + bqv) * QSC);
            kout[(size_t)r * HID + n] = __float2bfloat16(ak[nt][jj] + bkv);
            vT[(size_t)g * (HD * SEQ) + (size_t)d * SEQ + (rbase + jj) * 8 + blockIdx.y] =
                __float2bfloat16(av[nt][jj] + bvv);
        }
    }
}

// ---------------------------------------------------------------------------
// GEMM: out_f32[M x 512] = X_bf16 @ Wo_bf16^T + bo
// ---------------------------------------------------------------------------
__global__ __launch_bounds__(256) void gemm_out(const __hip_bfloat16* __restrict__ X,
                                                const __hip_bfloat16* __restrict__ W,
                                                const float* __restrict__ bias,
                                                float* __restrict__ out) {
    __shared__ __hip_bfloat16 Xs[64][LDP];
    __shared__ __hip_bfloat16 Ws[64][LDP];
    const int tid = threadIdx.x;
    const int w = tid >> 6, l = tid & 63;
    const int row0 = blockIdx.x * 64, col0 = blockIdx.y * 64;

    f32x4 acc[4] = {};
    for (int kt = 0; kt < 8; ++kt) {
        __syncthreads();
        for (int c = tid; c < 512; c += 256) {
            int r = c >> 3, col = (c & 7) * 8;
            *(uint4*)&Xs[r][col] = *(const uint4*)(X + (size_t)(row0 + r) * HID + kt * 64 + col);
            *(uint4*)&Ws[r][col] = *(const uint4*)(W + (size_t)(col0 + r) * HID + kt * 64 + col);
        }
        __syncthreads();
        for (int dk = 0; dk < 2; ++dk) {
            bf16x8 a = *(const bf16x8*)&Xs[w * 16 + (l & 15)][dk * 32 + 8 * (l >> 4)];
            for (int nt = 0; nt < 4; ++nt) {
                bf16x8 b = *(const bf16x8*)&Ws[nt * 16 + (l & 15)][dk * 32 + 8 * (l >> 4)];
                acc[nt] = MFMA(a, b, acc[nt]);
            }
        }
    }
    for (int nt = 0; nt < 4; ++nt) {
        int n = col0 + nt * 16 + (l & 15);
        float bv = bias[n];
        for (int jj = 0; jj < 4; ++jj) {
            int r = row0 + w * 16 + 4 * (l >> 4) + jj;
            out[(size_t)r * HID + n] = acc[nt][jj] + bv;
        }
    }
}

// ---------------------------------------------------------------------------
// Attention, T14 async-stage split: per k-tile, ds_write comes from registers
// prefetched in the PREVIOUS iteration; the next tile's global loads issue
// right after the stage barrier so HBM/L2 latency hides under QK+softmax+PV.
// Mask folded into the QK accumulator init (0 / -1e38); Q pre-scaled so
// softmax is a bare exp2f (one v_exp_f32). Ps fence barrier kept (round-6
// lesson: type-punned LDS write->read needs a full fence).
// ---------------------------------------------------------------------------
__global__ __launch_bounds__(256) void attn(const __hip_bfloat16* __restrict__ qg,
                                            const __hip_bfloat16* __restrict__ kg,
                                            const __hip_bfloat16* __restrict__ vT,
                                            const int* __restrict__ mask,
                                            __hip_bfloat16* __restrict__ wvt) {
    __shared__ __hip_bfloat16 Qs[64][LDP];
    __shared__ __hip_bfloat16 Ks[64][LDP];
    __shared__ __hip_bfloat16 VTs[64][LDP];
    __shared__ __hip_bfloat16 Ps[64][LDP];
    __shared__ float sbias[64];
    __shared__ float lpart[4][64];
    __shared__ float linv[64];

    const int tid = threadIdx.x;
    const int w = tid >> 6, l = tid & 63;
    // XCD-chunked swizzle: 1024 blocks % 8 == 0 -> bijective
    const int bid = (blockIdx.x & 7) * 128 + (blockIdx.x >> 3);
    const int g = bid >> 5, qt = bid & 31;
    const size_t hb = (size_t)g * (SEQ * HD);

    // stage Q tile (pre-scaled by QSC at projection)
    for (int c = tid; c < 512; c += 256) {
        int r = c >> 3, col = (c & 7) * 8;
        *(uint4*)&Qs[r][col] = *(const uint4*)(qg + hb + (size_t)(qt * 64 + r) * HD + col);
    }

    // staging coordinates: this thread owns elements c=tid and c=tid+256
    const int r0 = tid >> 3, r1 = (tid + 256) >> 3;
    const int cc0 = (tid & 7) * 8;
    // prefetch tile 0 into registers (named regs: static indexing)
    uint4 kp0 = *(const uint4*)(kg + hb + (size_t)r0 * HD + cc0);
    uint4 kp1 = *(const uint4*)(kg + hb + (size_t)r1 * HD + cc0);
    uint4 vp0 = *(const uint4*)(vT + hb + (size_t)r0 * SEQ + cc0);
    uint4 vp1 = *(const uint4*)(vT + hb + (size_t)r1 * SEQ + cc0);
    int mpre = (tid < 64) ? mask[tid] : 0;

    f32x4 acc[4] = {};
    float lacc = 0.f;

    for (int kt = 0; kt < 32; ++kt) {
        __syncthreads();   // previous iteration's LDS reads complete
        *(uint4*)&Ks[r0][cc0]  = kp0;
        *(uint4*)&Ks[r1][cc0]  = kp1;
        *(uint4*)&VTs[r0][cc0] = vp0;
        *(uint4*)&VTs[r1][cc0] = vp1;
        if (tid < 64) sbias[tid] = mpre ? 0.f : -1e38f;
        __syncthreads();   // tiles ready

        // issue next tile's global loads now; latency hides under compute
        if (kt < 31) {
            const size_t ko = hb + (size_t)(kt + 1) * 64 * HD;
            kp0 = *(const uint4*)(kg + ko + (size_t)r0 * HD + cc0);
            kp1 = *(const uint4*)(kg + ko + (size_t)r1 * HD + cc0);
            vp0 = *(const uint4*)(vT + hb + (size_t)r0 * SEQ + (kt + 1) * 64 + cc0);
            vp1 = *(const uint4*)(vT + hb + (size_t)r1 * SEQ + (kt + 1) * 64 + cc0);
            if (tid < 64) mpre = mask[(kt + 1) * 64 + tid];
        }

        // S = Q K^T, accumulator pre-loaded with the mask bias
        f32x4 sacc[4];
        for (int nt = 0; nt < 4; ++nt) {
            float mb = sbias[nt * 16 + (l & 15)];
            sacc[nt] = f32x4{mb, mb, mb, mb};
        }
        for (int dk = 0; dk < 2; ++dk) {
            bf16x8 a = *(const bf16x8*)&Qs[w * 16 + (l & 15)][dk * 32 + 8 * (l >> 4)];
            for (int nt = 0; nt < 4; ++nt) {
                bf16x8 b = *(const bf16x8*)&Ks[nt * 16 + (l & 15)][dk * 32 + 8 * (l >> 4)];
                sacc[nt] = MFMA(a, b, sacc[nt]);
            }
        }
        // p = exp2(s); masked cols have s = -1e38 -> p = 0
        for (int nt = 0; nt < 4; ++nt) {
            int kc = nt * 16 + (l & 15);
            for (int jj = 0; jj < 4; ++jj) {
                float p = exp2f(sacc[nt][jj]);
                Ps[w * 16 + 4 * (l >> 4) + jj][kc] = __float2bfloat16(p);
            }
        }
        __syncthreads();   // full LDS fence: order Ps stores before punned reads

        // row sums (each wave reads its own 16 rows)
        {
            int q = w * 16 + (l & 15), part = l >> 4;
            union { uint4 u; __hip_bfloat16 h[8]; } p0, p1;
            p0.u = *(const uint4*)&Ps[q][part * 16];
            p1.u = *(const uint4*)&Ps[q][part * 16 + 8];
            float s = 0.f;
            for (int j = 0; j < 8; ++j)
                s += __bfloat162float(p0.h[j]) + __bfloat162float(p1.h[j]);
            lacc += s;
        }
        // acc += P @ V
        for (int kk = 0; kk < 2; ++kk) {
            bf16x8 a = *(const bf16x8*)&Ps[w * 16 + (l & 15)][kk * 32 + 8 * (l >> 4)];
            for (int dt = 0; dt < 4; ++dt) {
                bf16x8 b = *(const bf16x8*)&VTs[dt * 16 + (l & 15)][kk * 32 + 8 * (l >> 4)];
                acc[dt] = MFMA(a, b, acc[dt]);
            }
        }
    }

    {
        int q = w * 16 + (l & 15), part = l >> 4;
        lpart[part][q] = lacc;
    }
    __syncthreads();
    if (tid < 64)
        linv[tid] = 1.f / (lpart[0][tid] + lpart[1][tid] + lpart[2][tid] + lpart[3][tid]);
    __syncthreads();

    const int qb4 = w * 16 + 4 * (l >> 4);
    const int ibase = qt * 64 + qb4;
    for (int dt = 0; dt < 4; ++dt) {
        int d = dt * 16 + (l & 15);
        union { __hip_bfloat16 h[4]; uint2 u; } o;
        for (int jj = 0; jj < 4; ++jj)
            o.h[jj] = __float2bfloat16(acc[dt][jj] * linv[qb4 + jj]);
        *(uint2*)(wvt + (size_t)g * (HD * SEQ) + (size_t)d * SEQ + ibase) = o.u;
    }
}

// ---------------------------------------------------------------------------
// ws layout (26 MB peak): Xb [0,8MB) -> aliased by wvt after QKV GEMM;
// W bf16 [8,10MB); qb [10,18MB); kb [18,26MB).
// vT lives in d_out's first 8 MB (dead before gemm_out overwrites d_out).
// ---------------------------------------------------------------------------
extern "C" void kernel_launch(void* const* d_in, const int* in_sizes, int n_in,
                              void* d_out, int out_size, void* d_ws, size_t ws_size,
                              hipStream_t stream) {
    const float* lstm = (const float*)d_in[0];
    const int* mask = (const int*)d_in[1];
    const float* Wq = (const float*)d_in[2]; const float* bq = (const float*)d_in[3];
    const float* Wk = (const float*)d_in[4]; const float* bk = (const float*)d_in[5];
    const float* Wv = (const float*)d_in[6]; const float* bv = (const float*)d_in[7];
    const float* Wo = (const float*)d_in[8]; const float* bo = (const float*)d_in[9];
    float* out = (float*)d_out;

    const size_t NX = (size_t)MROWS * HID;    // 4M elems
    const size_t NW = (size_t)HID * HID;      // 256K elems
    __hip_bfloat16* Xb  = (__hip_bfloat16*)d_ws;            // 4M elems (8MB)
    __hip_bfloat16* Wqb = Xb + NX;                          // 256K
    __hip_bfloat16* Wkb = Wqb + NW;
    __hip_bfloat16* Wvb = Wkb + NW;
    __hip_bfloat16* Wob = Wvb + NW;
    __hip_bfloat16* qb  = Wob + NW;                         // 4M
    __hip_bfloat16* kb  = qb + NX;                          // 4M
    __hip_bfloat16* vT  = (__hip_bfloat16*)d_out;           // scratch in d_out[0,8MB)
    __hip_bfloat16* wvt = Xb;                               // alias: Xb dead after QKV GEMM

    conv_x<<<2048, 256, 0, stream>>>(lstm, Xb, (int)(NX / 4));
    conv_w<<<dim3(256, 4), 256, 0, stream>>>(Wq, Wk, Wv, Wo, Wqb);

    dim3 gg(MROWS / 64, HID / 64), bb(256);
    gemm_qkv_fused<<<gg, bb, 0, stream>>>(Xb, Wqb, Wkb, Wvb, bq, bk, bv, qb, kb, vT);
    attn<<<dim3(NG * (SEQ / 64)), bb, 0, stream>>>(qb, kb, vT, mask, wvt);
    gemm_out<<<gg, bb, 0, stream>>>(wvt, Wob, bo, out);
}

// Round 10
// 151.316 us; speedup vs baseline: 1.6398x; 1.0693x over previous
//
#include <hip/hip_runtime.h>
#include <hip/hip_bf16.h>

// Problem constants
#define HID 512
#define SEQ 2048
#define NG 32            // (B*NUM_HEADS) after the faithful-to-source flat reshape
#define HD 64
#define MROWS 8192       // B*SEQ
#define LDP 72           // padded LDS row stride (elems) = 144B
// 1/sqrt(512) * log2(e): folded into Q so softmax is exp2(s)
#define QSC 0.0637587178f

typedef __bf16 bf16x8 __attribute__((ext_vector_type(8)));
typedef float f32x4 __attribute__((ext_vector_type(4)));

#define MFMA(a, b, c) __builtin_amdgcn_mfma_f32_16x16x32_bf16((a), (b), (c), 0, 0, 0)

// ---------------------------------------------------------------------------
// prep: f32 -> bf16 vectorized converts
// ---------------------------------------------------------------------------
__global__ __launch_bounds__(256) void conv_x(const float* __restrict__ src,
                                              __hip_bfloat16* __restrict__ dst, int n4) {
    int stride = gridDim.x * 256;
    for (int i = blockIdx.x * 256 + threadIdx.x; i < n4; i += stride) {
        float4 v = *(const float4*)(src + (size_t)i * 4);
        union { __hip_bfloat16 h[4]; uint2 u; } p;
        p.h[0] = __float2bfloat16(v.x); p.h[1] = __float2bfloat16(v.y);
        p.h[2] = __float2bfloat16(v.z); p.h[3] = __float2bfloat16(v.w);
        *(uint2*)(dst + (size_t)i * 4) = p.u;
    }
}

__global__ __launch_bounds__(256) void conv_w(const float* __restrict__ a,
                                              const float* __restrict__ b,
                                              const float* __restrict__ c,
                                              const float* __restrict__ d,
                                              __hip_bfloat16* __restrict__ out) {
    int which = blockIdx.y;
    const float* s = which == 0 ? a : (which == 1 ? b : (which == 2 ? c : d));
    __hip_bfloat16* o = out + (size_t)which * (HID * HID);
    int i = blockIdx.x * 256 + threadIdx.x;   // 65536 float4 per W
    float4 v = *(const float4*)(s + (size_t)i * 4);
    union { __hip_bfloat16 h[4]; uint2 u; } p;
    p.h[0] = __float2bfloat16(v.x); p.h[1] = __float2bfloat16(v.y);
    p.h[2] = __float2bfloat16(v.z); p.h[3] = __float2bfloat16(v.w);
    *(uint2*)(o + (size_t)i * 4) = p.u;
}

// ---------------------------------------------------------------------------
// Fused QKV GEMM with T14 register prefetch across the stage barrier.
// q pre-scaled by QSC; v written transposed per head: vT[g][d][i].
// ---------------------------------------------------------------------------
__global__ __launch_bounds__(256) void gemm_qkv_fused(
        const __hip_bfloat16* __restrict__ Xb,
        const __hip_bfloat16* __restrict__ Wqb, const __hip_bfloat16* __restrict__ Wkb,
        const __hip_bfloat16* __restrict__ Wvb,
        const float* __restrict__ bq, const float* __restrict__ bk, const float* __restrict__ bv,
        __hip_bfloat16* __restrict__ qout, __hip_bfloat16* __restrict__ kout,
        __hip_bfloat16* __restrict__ vT) {
    __shared__ __hip_bfloat16 Xs[64][LDP];
    __shared__ __hip_bfloat16 Wqs[64][LDP];
    __shared__ __hip_bfloat16 Wks[64][LDP];
    __shared__ __hip_bfloat16 Wvs[64][LDP];
    const int tid = threadIdx.x;
    const int w = tid >> 6, l = tid & 63;
    const int row0 = blockIdx.x * 64, col0 = blockIdx.y * 64;

    const int r0 = tid >> 3, r1 = (tid + 256) >> 3;
    const int cc0 = (tid & 7) * 8;
    uint4 px0, px1, pq0, pq1, pk0, pk1, pv0, pv1;
    {
        px0 = *(const uint4*)(Xb  + (size_t)(row0 + r0) * HID + cc0);
        px1 = *(const uint4*)(Xb  + (size_t)(row0 + r1) * HID + cc0);
        pq0 = *(const uint4*)(Wqb + (size_t)(col0 + r0) * HID + cc0);
        pq1 = *(const uint4*)(Wqb + (size_t)(col0 + r1) * HID + cc0);
        pk0 = *(const uint4*)(Wkb + (size_t)(col0 + r0) * HID + cc0);
        pk1 = *(const uint4*)(Wkb + (size_t)(col0 + r1) * HID + cc0);
        pv0 = *(const uint4*)(Wvb + (size_t)(col0 + r0) * HID + cc0);
        pv1 = *(const uint4*)(Wvb + (size_t)(col0 + r1) * HID + cc0);
    }

    f32x4 aq[4] = {}, ak[4] = {}, av[4] = {};
    for (int kt = 0; kt < 8; ++kt) {
        __syncthreads();
        *(uint4*)&Xs[r0][cc0]  = px0;  *(uint4*)&Xs[r1][cc0]  = px1;
        *(uint4*)&Wqs[r0][cc0] = pq0;  *(uint4*)&Wqs[r1][cc0] = pq1;
        *(uint4*)&Wks[r0][cc0] = pk0;  *(uint4*)&Wks[r1][cc0] = pk1;
        *(uint4*)&Wvs[r0][cc0] = pv0;  *(uint4*)&Wvs[r1][cc0] = pv1;
        __syncthreads();
        if (kt < 7) {
            size_t go = (size_t)(kt + 1) * 64 + cc0;
            px0 = *(const uint4*)(Xb  + (size_t)(row0 + r0) * HID + go);
            px1 = *(const uint4*)(Xb  + (size_t)(row0 + r1) * HID + go);
            pq0 = *(const uint4*)(Wqb + (size_t)(col0 + r0) * HID + go);
            pq1 = *(const uint4*)(Wqb + (size_t)(col0 + r1) * HID + go);
            pk0 = *(const uint4*)(Wkb + (size_t)(col0 + r0) * HID + go);
            pk1 = *(const uint4*)(Wkb + (size_t)(col0 + r1) * HID + go);
            pv0 = *(const uint4*)(Wvb + (size_t)(col0 + r0) * HID + go);
            pv1 = *(const uint4*)(Wvb + (size_t)(col0 + r1) * HID + go);
        }
        for (int dk = 0; dk < 2; ++dk) {
            bf16x8 a = *(const bf16x8*)&Xs[w * 16 + (l & 15)][dk * 32 + 8 * (l >> 4)];
            for (int nt = 0; nt < 4; ++nt) {
                int rr = nt * 16 + (l & 15), cc = dk * 32 + 8 * (l >> 4);
                aq[nt] = MFMA(a, *(const bf16x8*)&Wqs[rr][cc], aq[nt]);
                ak[nt] = MFMA(a, *(const bf16x8*)&Wks[rr][cc], ak[nt]);
                av[nt] = MFMA(a, *(const bf16x8*)&Wvs[rr][cc], av[nt]);
            }
        }
    }
    // epilogue
    const int g = row0 >> 8;
    const int rbase = (row0 & 255) + w * 16 + 4 * (l >> 4);
    for (int nt = 0; nt < 4; ++nt) {
        int n = col0 + nt * 16 + (l & 15);
        float bqv = bq[n], bkv = bk[n], bvv = bv[n];
        int d = n & 63;   // col0 is a multiple of 64
        for (int jj = 0; jj < 4; ++jj) {
            int r = row0 + w * 16 + 4 * (l >> 4) + jj;
            qout[(size_t)r * HID + n] = __float2bfloat16((aq[nt][jj] + bqv) * QSC);
            kout[(size_t)r * HID + n] = __float2bfloat16(ak[nt][jj] + bkv);
            vT[(size_t)g * (HD * SEQ) + (size_t)d * SEQ + (rbase + jj) * 8 + blockIdx.y] =
                __float2bfloat16(av[nt][jj] + bvv);
        }
    }
}

// ---------------------------------------------------------------------------
// GEMM: out_f32[M x 512] = X_bf16 @ Wo_bf16^T + bo, with T14 reg prefetch.
// ---------------------------------------------------------------------------
__global__ __launch_bounds__(256) void gemm_out(const __hip_bfloat16* __restrict__ X,
                                                const __hip_bfloat16* __restrict__ W,
                                                const float* __restrict__ bias,
                                                float* __restrict__ out) {
    __shared__ __hip_bfloat16 Xs[64][LDP];
    __shared__ __hip_bfloat16 Ws[64][LDP];
    const int tid = threadIdx.x;
    const int w = tid >> 6, l = tid & 63;
    const int row0 = blockIdx.x * 64, col0 = blockIdx.y * 64;

    const int r0 = tid >> 3, r1 = (tid + 256) >> 3;
    const int cc0 = (tid & 7) * 8;
    uint4 px0 = *(const uint4*)(X + (size_t)(row0 + r0) * HID + cc0);
    uint4 px1 = *(const uint4*)(X + (size_t)(row0 + r1) * HID + cc0);
    uint4 pw0 = *(const uint4*)(W + (size_t)(col0 + r0) * HID + cc0);
    uint4 pw1 = *(const uint4*)(W + (size_t)(col0 + r1) * HID + cc0);

    f32x4 acc[4] = {};
    for (int kt = 0; kt < 8; ++kt) {
        __syncthreads();
        *(uint4*)&Xs[r0][cc0] = px0;  *(uint4*)&Xs[r1][cc0] = px1;
        *(uint4*)&Ws[r0][cc0] = pw0;  *(uint4*)&Ws[r1][cc0] = pw1;
        __syncthreads();
        if (kt < 7) {
            size_t go = (size_t)(kt + 1) * 64 + cc0;
            px0 = *(const uint4*)(X + (size_t)(row0 + r0) * HID + go);
            px1 = *(const uint4*)(X + (size_t)(row0 + r1) * HID + go);
            pw0 = *(const uint4*)(W + (size_t)(col0 + r0) * HID + go);
            pw1 = *(const uint4*)(W + (size_t)(col0 + r1) * HID + go);
        }
        for (int dk = 0; dk < 2; ++dk) {
            bf16x8 a = *(const bf16x8*)&Xs[w * 16 + (l & 15)][dk * 32 + 8 * (l >> 4)];
            for (int nt = 0; nt < 4; ++nt) {
                bf16x8 b = *(const bf16x8*)&Ws[nt * 16 + (l & 15)][dk * 32 + 8 * (l >> 4)];
                acc[nt] = MFMA(a, b, acc[nt]);
            }
        }
    }
    for (int nt = 0; nt < 4; ++nt) {
        int n = col0 + nt * 16 + (l & 15);
        float bv = bias[n];
        for (int jj = 0; jj < 4; ++jj) {
            int r = row0 + w * 16 + 4 * (l >> 4) + jj;
            out[(size_t)r * HID + n] = acc[nt][jj] + bv;
        }
    }
}

// ---------------------------------------------------------------------------
// Attention. T14 reg-prefetch staging; mask as accumulator bias; softmax =
// bare exp2f. Row-sums computed BY THE MATRIX PIPE: an all-ones B operand
// MFMA in the PV loop makes every acc column hold the row-sum, and each lane
// then owns exactly the sums for its own 4 output rows -> no LDS reduction,
// no epilogue barriers. Ps fence barrier kept (round-6 lesson).
// ---------------------------------------------------------------------------
__global__ __launch_bounds__(256) void attn(const __hip_bfloat16* __restrict__ qg,
                                            const __hip_bfloat16* __restrict__ kg,
                                            const __hip_bfloat16* __restrict__ vT,
                                            const int* __restrict__ mask,
                                            __hip_bfloat16* __restrict__ wvt) {
    __shared__ __hip_bfloat16 Qs[64][LDP];
    __shared__ __hip_bfloat16 Ks[64][LDP];
    __shared__ __hip_bfloat16 VTs[64][LDP];
    __shared__ __hip_bfloat16 Ps[64][LDP];
    __shared__ float sbias[64];

    const int tid = threadIdx.x;
    const int w = tid >> 6, l = tid & 63;
    // XCD-chunked swizzle: 1024 blocks % 8 == 0 -> bijective
    const int bid = (blockIdx.x & 7) * 128 + (blockIdx.x >> 3);
    const int g = bid >> 5, qt = bid & 31;
    const size_t hb = (size_t)g * (SEQ * HD);

    // stage Q tile (pre-scaled by QSC at projection)
    for (int c = tid; c < 512; c += 256) {
        int r = c >> 3, col = (c & 7) * 8;
        *(uint4*)&Qs[r][col] = *(const uint4*)(qg + hb + (size_t)(qt * 64 + r) * HD + col);
    }

    const int r0 = tid >> 3, r1 = (tid + 256) >> 3;
    const int cc0 = (tid & 7) * 8;
    uint4 kp0 = *(const uint4*)(kg + hb + (size_t)r0 * HD + cc0);
    uint4 kp1 = *(const uint4*)(kg + hb + (size_t)r1 * HD + cc0);
    uint4 vp0 = *(const uint4*)(vT + hb + (size_t)r0 * SEQ + cc0);
    uint4 vp1 = *(const uint4*)(vT + hb + (size_t)r1 * SEQ + cc0);
    int mpre = (tid < 64) ? mask[tid] : 0;

    const __bf16 kOne = (__bf16)1.0f;
    const bf16x8 ones = {kOne, kOne, kOne, kOne, kOne, kOne, kOne, kOne};

    f32x4 acc[4] = {};
    f32x4 lsum = {};

    for (int kt = 0; kt < 32; ++kt) {
        __syncthreads();   // previous iteration's LDS reads complete
        *(uint4*)&Ks[r0][cc0]  = kp0;
        *(uint4*)&Ks[r1][cc0]  = kp1;
        *(uint4*)&VTs[r0][cc0] = vp0;
        *(uint4*)&VTs[r1][cc0] = vp1;
        if (tid < 64) sbias[tid] = mpre ? 0.f : -1e38f;
        __syncthreads();   // tiles ready

        // issue next tile's global loads now; latency hides under compute
        if (kt < 31) {
            const size_t ko = hb + (size_t)(kt + 1) * 64 * HD;
            kp0 = *(const uint4*)(kg + ko + (size_t)r0 * HD + cc0);
            kp1 = *(const uint4*)(kg + ko + (size_t)r1 * HD + cc0);
            vp0 = *(const uint4*)(vT + hb + (size_t)r0 * SEQ + (kt + 1) * 64 + cc0);
            vp1 = *(const uint4*)(vT + hb + (size_t)r1 * SEQ + (kt + 1) * 64 + cc0);
            if (tid < 64) mpre = mask[(kt + 1) * 64 + tid];
        }

        // S = Q K^T, accumulator pre-loaded with the mask bias
        f32x4 sacc[4];
        for (int nt = 0; nt < 4; ++nt) {
            float mb = sbias[nt * 16 + (l & 15)];
            sacc[nt] = f32x4{mb, mb, mb, mb};
        }
        for (int dk = 0; dk < 2; ++dk) {
            bf16x8 a = *(const bf16x8*)&Qs[w * 16 + (l & 15)][dk * 32 + 8 * (l >> 4)];
            for (int nt = 0; nt < 4; ++nt) {
                bf16x8 b = *(const bf16x8*)&Ks[nt * 16 + (l & 15)][dk * 32 + 8 * (l >> 4)];
                sacc[nt] = MFMA(a, b, sacc[nt]);
            }
        }
        // p = exp2(s); masked cols have s = -1e38 -> p = 0
        for (int nt = 0; nt < 4; ++nt) {
            int kc = nt * 16 + (l & 15);
            for (int jj = 0; jj < 4; ++jj) {
                float p = exp2f(sacc[nt][jj]);
                Ps[w * 16 + 4 * (l >> 4) + jj][kc] = __float2bfloat16(p);
            }
        }
        __syncthreads();   // full LDS fence: order Ps stores before punned reads

        // acc += P @ V ; lsum += P @ ones (row-sum on the matrix pipe)
        for (int kk = 0; kk < 2; ++kk) {
            bf16x8 a = *(const bf16x8*)&Ps[w * 16 + (l & 15)][kk * 32 + 8 * (l >> 4)];
            lsum = MFMA(a, ones, lsum);
            for (int dt = 0; dt < 4; ++dt) {
                bf16x8 b = *(const bf16x8*)&VTs[dt * 16 + (l & 15)][kk * 32 + 8 * (l >> 4)];
                acc[dt] = MFMA(a, b, acc[dt]);
            }
        }
    }

    // lane's lsum[jj] IS the row-sum for its acc row jj (all-ones B => every
    // output column holds the row-sum; this lane's column is l&15).
    float rinv[4];
    for (int jj = 0; jj < 4; ++jj) rinv[jj] = 1.f / lsum[jj];

    const int ibase = qt * 64 + w * 16 + 4 * (l >> 4);
    for (int dt = 0; dt < 4; ++dt) {
        int d = dt * 16 + (l & 15);
        union { __hip_bfloat16 h[4]; uint2 u; } o;
        for (int jj = 0; jj < 4; ++jj)
            o.h[jj] = __float2bfloat16(acc[dt][jj] * rinv[jj]);
        *(uint2*)(wvt + (size_t)g * (HD * SEQ) + (size_t)d * SEQ + ibase) = o.u;
    }
}

// ---------------------------------------------------------------------------
// ws layout (26 MB peak): Xb [0,8MB) -> aliased by wvt after QKV GEMM;
// W bf16 [8,10MB); qb [10,18MB); kb [18,26MB).
// vT lives in d_out's first 8 MB (dead before gemm_out overwrites d_out).
// ---------------------------------------------------------------------------
extern "C" void kernel_launch(void* const* d_in, const int* in_sizes, int n_in,
                              void* d_out, int out_size, void* d_ws, size_t ws_size,
                              hipStream_t stream) {
    const float* lstm = (const float*)d_in[0];
    const int* mask = (const int*)d_in[1];
    const float* Wq = (const float*)d_in[2]; const float* bq = (const float*)d_in[3];
    const float* Wk = (const float*)d_in[4]; const float* bk = (const float*)d_in[5];
    const float* Wv = (const float*)d_in[6]; const float* bv = (const float*)d_in[7];
    const float* Wo = (const float*)d_in[8]; const float* bo = (const float*)d_in[9];
    float* out = (float*)d_out;

    const size_t NX = (size_t)MROWS * HID;    // 4M elems
    const size_t NW = (size_t)HID * HID;      // 256K elems
    __hip_bfloat16* Xb  = (__hip_bfloat16*)d_ws;            // 4M elems (8MB)
    __hip_bfloat16* Wqb = Xb + NX;                          // 256K
    __hip_bfloat16* Wkb = Wqb + NW;
    __hip_bfloat16* Wvb = Wkb + NW;
    __hip_bfloat16* Wob = Wvb + NW;
    __hip_bfloat16* qb  = Wob + NW;                         // 4M
    __hip_bfloat16* kb  = qb + NX;                          // 4M
    __hip_bfloat16* vT  = (__hip_bfloat16*)d_out;           // scratch in d_out[0,8MB)
    __hip_bfloat16* wvt = Xb;                               // alias: Xb dead after QKV GEMM

    conv_x<<<2048, 256, 0, stream>>>(lstm, Xb, (int)(NX / 4));
    conv_w<<<dim3(256, 4), 256, 0, stream>>>(Wq, Wk, Wv, Wo, Wqb);

    dim3 gg(MROWS / 64, HID / 64), bb(256);
    gemm_qkv_fused<<<gg, bb, 0, stream>>>(Xb, Wqb, Wkb, Wvb, bq, bk, bv, qb, kb, vT);
    attn<<<dim3(NG * (SEQ / 64)), bb, 0, stream>>>(qb, kb, vT, mask, wvt);
    gemm_out<<<gg, bb, 0, stream>>>(wvt, Wob, bo, out);
}

// Round 11
// 147.977 us; speedup vs baseline: 1.6768x; 1.0226x over previous
//
#include <hip/hip_runtime.h>
#include <hip/hip_bf16.h>

// Problem constants
#define HID 512
#define SEQ 2048
#define NG 32            // (B*NUM_HEADS) after the faithful-to-source flat reshape
#define HD 64
#define MROWS 8192       // B*SEQ
#define LDP 72           // padded LDS row stride (elems) = 144B
// 1/sqrt(512) * log2(e): folded into Q so softmax is exp2(s)
#define QSC 0.0637587178f

typedef __bf16 bf16x8 __attribute__((ext_vector_type(8)));
typedef float f32x4 __attribute__((ext_vector_type(4)));

#define MFMA(a, b, c) __builtin_amdgcn_mfma_f32_16x16x32_bf16((a), (b), (c), 0, 0, 0)

// ---------------------------------------------------------------------------
// prep: f32 -> bf16 vectorized converts
// ---------------------------------------------------------------------------
__global__ __launch_bounds__(256) void conv_x(const float* __restrict__ src,
                                              __hip_bfloat16* __restrict__ dst, int n4) {
    int stride = gridDim.x * 256;
    for (int i = blockIdx.x * 256 + threadIdx.x; i < n4; i += stride) {
        float4 v = *(const float4*)(src + (size_t)i * 4);
        union { __hip_bfloat16 h[4]; uint2 u; } p;
        p.h[0] = __float2bfloat16(v.x); p.h[1] = __float2bfloat16(v.y);
        p.h[2] = __float2bfloat16(v.z); p.h[3] = __float2bfloat16(v.w);
        *(uint2*)(dst + (size_t)i * 4) = p.u;
    }
}

__global__ __launch_bounds__(256) void conv_w(const float* __restrict__ a,
                                              const float* __restrict__ b,
                                              const float* __restrict__ c,
                                              const float* __restrict__ d,
                                              __hip_bfloat16* __restrict__ out) {
    int which = blockIdx.y;
    const float* s = which == 0 ? a : (which == 1 ? b : (which == 2 ? c : d));
    __hip_bfloat16* o = out + (size_t)which * (HID * HID);
    int i = blockIdx.x * 256 + threadIdx.x;   // 65536 float4 per W
    float4 v = *(const float4*)(s + (size_t)i * 4);
    union { __hip_bfloat16 h[4]; uint2 u; } p;
    p.h[0] = __float2bfloat16(v.x); p.h[1] = __float2bfloat16(v.y);
    p.h[2] = __float2bfloat16(v.z); p.h[3] = __float2bfloat16(v.w);
    *(uint2*)(o + (size_t)i * 4) = p.u;
}

// ---------------------------------------------------------------------------
// Fused QKV GEMM with T14 register prefetch across the stage barrier.
// q pre-scaled by QSC; v written transposed per head: vT[g][d][i].
// ---------------------------------------------------------------------------
__global__ __launch_bounds__(256) void gemm_qkv_fused(
        const __hip_bfloat16* __restrict__ Xb,
        const __hip_bfloat16* __restrict__ Wqb, const __hip_bfloat16* __restrict__ Wkb,
        const __hip_bfloat16* __restrict__ Wvb,
        const float* __restrict__ bq, const float* __restrict__ bk, const float* __restrict__ bv,
        __hip_bfloat16* __restrict__ qout, __hip_bfloat16* __restrict__ kout,
        __hip_bfloat16* __restrict__ vT) {
    __shared__ __hip_bfloat16 Xs[64][LDP];
    __shared__ __hip_bfloat16 Wqs[64][LDP];
    __shared__ __hip_bfloat16 Wks[64][LDP];
    __shared__ __hip_bfloat16 Wvs[64][LDP];
    const int tid = threadIdx.x;
    const int w = tid >> 6, l = tid & 63;
    const int row0 = blockIdx.x * 64, col0 = blockIdx.y * 64;

    const int r0 = tid >> 3, r1 = (tid + 256) >> 3;
    const int cc0 = (tid & 7) * 8;
    uint4 px0, px1, pq0, pq1, pk0, pk1, pv0, pv1;
    {
        px0 = *(const uint4*)(Xb  + (size_t)(row0 + r0) * HID + cc0);
        px1 = *(const uint4*)(Xb  + (size_t)(row0 + r1) * HID + cc0);
        pq0 = *(const uint4*)(Wqb + (size_t)(col0 + r0) * HID + cc0);
        pq1 = *(const uint4*)(Wqb + (size_t)(col0 + r1) * HID + cc0);
        pk0 = *(const uint4*)(Wkb + (size_t)(col0 + r0) * HID + cc0);
        pk1 = *(const uint4*)(Wkb + (size_t)(col0 + r1) * HID + cc0);
        pv0 = *(const uint4*)(Wvb + (size_t)(col0 + r0) * HID + cc0);
        pv1 = *(const uint4*)(Wvb + (size_t)(col0 + r1) * HID + cc0);
    }

    f32x4 aq[4] = {}, ak[4] = {}, av[4] = {};
    for (int kt = 0; kt < 8; ++kt) {
        __syncthreads();
        *(uint4*)&Xs[r0][cc0]  = px0;  *(uint4*)&Xs[r1][cc0]  = px1;
        *(uint4*)&Wqs[r0][cc0] = pq0;  *(uint4*)&Wqs[r1][cc0] = pq1;
        *(uint4*)&Wks[r0][cc0] = pk0;  *(uint4*)&Wks[r1][cc0] = pk1;
        *(uint4*)&Wvs[r0][cc0] = pv0;  *(uint4*)&Wvs[r1][cc0] = pv1;
        __syncthreads();
        if (kt < 7) {
            size_t go = (size_t)(kt + 1) * 64 + cc0;
            px0 = *(const uint4*)(Xb  + (size_t)(row0 + r0) * HID + go);
            px1 = *(const uint4*)(Xb  + (size_t)(row0 + r1) * HID + go);
            pq0 = *(const uint4*)(Wqb + (size_t)(col0 + r0) * HID + go);
            pq1 = *(const uint4*)(Wqb + (size_t)(col0 + r1) * HID + go);
            pk0 = *(const uint4*)(Wkb + (size_t)(col0 + r0) * HID + go);
            pk1 = *(const uint4*)(Wkb + (size_t)(col0 + r1) * HID + go);
            pv0 = *(const uint4*)(Wvb + (size_t)(col0 + r0) * HID + go);
            pv1 = *(const uint4*)(Wvb + (size_t)(col0 + r1) * HID + go);
        }
        for (int dk = 0; dk < 2; ++dk) {
            bf16x8 a = *(const bf16x8*)&Xs[w * 16 + (l & 15)][dk * 32 + 8 * (l >> 4)];
            for (int nt = 0; nt < 4; ++nt) {
                int rr = nt * 16 + (l & 15), cc = dk * 32 + 8 * (l >> 4);
                aq[nt] = MFMA(a, *(const bf16x8*)&Wqs[rr][cc], aq[nt]);
                ak[nt] = MFMA(a, *(const bf16x8*)&Wks[rr][cc], ak[nt]);
                av[nt] = MFMA(a, *(const bf16x8*)&Wvs[rr][cc], av[nt]);
            }
        }
    }
    // epilogue
    const int g = row0 >> 8;
    const int rbase = (row0 & 255) + w * 16 + 4 * (l >> 4);
    for (int nt = 0; nt < 4; ++nt) {
        int n = col0 + nt * 16 + (l & 15);
        float bqv = bq[n], bkv = bk[n], bvv = bv[n];
        int d = n & 63;   // col0 is a multiple of 64
        for (int jj = 0; jj < 4; ++jj) {
            int r = row0 + w * 16 + 4 * (l >> 4) + jj;
            qout[(size_t)r * HID + n] = __float2bfloat16((aq[nt][jj] + bqv) * QSC);
            kout[(size_t)r * HID + n] = __float2bfloat16(ak[nt][jj] + bkv);
            vT[(size_t)g * (HD * SEQ) + (size_t)d * SEQ + (rbase + jj) * 8 + blockIdx.y] =
                __float2bfloat16(av[nt][jj] + bvv);
        }
    }
}

// ---------------------------------------------------------------------------
// GEMM: out_f32[M x 512] = X_bf16 @ Wo_bf16^T + bo, with T14 reg prefetch.
// ---------------------------------------------------------------------------
__global__ __launch_bounds__(256) void gemm_out(const __hip_bfloat16* __restrict__ X,
                                                const __hip_bfloat16* __restrict__ W,
                                                const float* __restrict__ bias,
                                                float* __restrict__ out) {
    __shared__ __hip_bfloat16 Xs[64][LDP];
    __shared__ __hip_bfloat16 Ws[64][LDP];
    const int tid = threadIdx.x;
    const int w = tid >> 6, l = tid & 63;
    const int row0 = blockIdx.x * 64, col0 = blockIdx.y * 64;

    const int r0 = tid >> 3, r1 = (tid + 256) >> 3;
    const int cc0 = (tid & 7) * 8;
    uint4 px0 = *(const uint4*)(X + (size_t)(row0 + r0) * HID + cc0);
    uint4 px1 = *(const uint4*)(X + (size_t)(row0 + r1) * HID + cc0);
    uint4 pw0 = *(const uint4*)(W + (size_t)(col0 + r0) * HID + cc0);
    uint4 pw1 = *(const uint4*)(W + (size_t)(col0 + r1) * HID + cc0);

    f32x4 acc[4] = {};
    for (int kt = 0; kt < 8; ++kt) {
        __syncthreads();
        *(uint4*)&Xs[r0][cc0] = px0;  *(uint4*)&Xs[r1][cc0] = px1;
        *(uint4*)&Ws[r0][cc0] = pw0;  *(uint4*)&Ws[r1][cc0] = pw1;
        __syncthreads();
        if (kt < 7) {
            size_t go = (size_t)(kt + 1) * 64 + cc0;
            px0 = *(const uint4*)(X + (size_t)(row0 + r0) * HID + go);
            px1 = *(const uint4*)(X + (size_t)(row0 + r1) * HID + go);
            pw0 = *(const uint4*)(W + (size_t)(col0 + r0) * HID + go);
            pw1 = *(const uint4*)(W + (size_t)(col0 + r1) * HID + go);
        }
        for (int dk = 0; dk < 2; ++dk) {
            bf16x8 a = *(const bf16x8*)&Xs[w * 16 + (l & 15)][dk * 32 + 8 * (l >> 4)];
            for (int nt = 0; nt < 4; ++nt) {
                bf16x8 b = *(const bf16x8*)&Ws[nt * 16 + (l & 15)][dk * 32 + 8 * (l >> 4)];
                acc[nt] = MFMA(a, b, acc[nt]);
            }
        }
    }
    for (int nt = 0; nt < 4; ++nt) {
        int n = col0 + nt * 16 + (l & 15);
        float bv = bias[n];
        for (int jj = 0; jj < 4; ++jj) {
            int r = row0 + w * 16 + 4 * (l >> 4) + jj;
            out[(size_t)r * HID + n] = acc[nt][jj] + bv;
        }
    }
}

// ---------------------------------------------------------------------------
// Attention, QBLK=128: 4 waves x 32 queries each (2 m-subtiles of 16), so
// every K/V LDS fragment read is amortized over 2x queries (LDS-BW was the
// round-10 bottleneck: ~48 of 90 us). Q fragments live in REGISTERS (loaded
// once from global; Qs LDS array eliminated). T14 reg-prefetch staging; mask
// as accumulator bias; softmax = bare exp2f; row-sums on the matrix pipe via
// all-ones MFMA. Ps fence barrier kept (round-6 lesson).
// ---------------------------------------------------------------------------
__global__ __launch_bounds__(256) void attn(const __hip_bfloat16* __restrict__ qg,
                                            const __hip_bfloat16* __restrict__ kg,
                                            const __hip_bfloat16* __restrict__ vT,
                                            const int* __restrict__ mask,
                                            __hip_bfloat16* __restrict__ wvt) {
    __shared__ __hip_bfloat16 Ks[64][LDP];
    __shared__ __hip_bfloat16 VTs[64][LDP];
    __shared__ __hip_bfloat16 Ps[128][LDP];
    __shared__ float sbias[64];

    const int tid = threadIdx.x;
    const int w = tid >> 6, l = tid & 63;
    const int h = l >> 4, q = l & 15;
    // XCD-chunked swizzle: 512 blocks % 8 == 0 -> bijective
    const int bid = (blockIdx.x & 7) * 64 + (blockIdx.x >> 3);
    const int g = bid >> 4, qt = bid & 15;
    const size_t hb = (size_t)g * (SEQ * HD);

    // Q fragments in registers (one-time global read, L2-resident)
    bf16x8 qf[2][2];
    for (int m = 0; m < 2; ++m)
        for (int dk = 0; dk < 2; ++dk)
            qf[m][dk] = *(const bf16x8*)(qg + hb +
                (size_t)(qt * 128 + w * 32 + m * 16 + q) * HD + dk * 32 + 8 * h);

    const int r0 = tid >> 3, r1 = (tid + 256) >> 3;
    const int cc0 = (tid & 7) * 8;
    uint4 kp0 = *(const uint4*)(kg + hb + (size_t)r0 * HD + cc0);
    uint4 kp1 = *(const uint4*)(kg + hb + (size_t)r1 * HD + cc0);
    uint4 vp0 = *(const uint4*)(vT + hb + (size_t)r0 * SEQ + cc0);
    uint4 vp1 = *(const uint4*)(vT + hb + (size_t)r1 * SEQ + cc0);
    int mpre = (tid < 64) ? mask[tid] : 0;

    const __bf16 kOne = (__bf16)1.0f;
    const bf16x8 ones = {kOne, kOne, kOne, kOne, kOne, kOne, kOne, kOne};

    f32x4 acc[2][4] = {};
    f32x4 lsum[2] = {};

    for (int kt = 0; kt < 32; ++kt) {
        __syncthreads();   // previous iteration's LDS reads complete
        *(uint4*)&Ks[r0][cc0]  = kp0;
        *(uint4*)&Ks[r1][cc0]  = kp1;
        *(uint4*)&VTs[r0][cc0] = vp0;
        *(uint4*)&VTs[r1][cc0] = vp1;
        if (tid < 64) sbias[tid] = mpre ? 0.f : -1e38f;
        __syncthreads();   // tiles ready

        // issue next tile's global loads now; latency hides under compute
        if (kt < 31) {
            const size_t ko = hb + (size_t)(kt + 1) * 64 * HD;
            kp0 = *(const uint4*)(kg + ko + (size_t)r0 * HD + cc0);
            kp1 = *(const uint4*)(kg + ko + (size_t)r1 * HD + cc0);
            vp0 = *(const uint4*)(vT + hb + (size_t)r0 * SEQ + (kt + 1) * 64 + cc0);
            vp1 = *(const uint4*)(vT + hb + (size_t)r1 * SEQ + (kt + 1) * 64 + cc0);
            if (tid < 64) mpre = mask[(kt + 1) * 64 + tid];
        }

        // S = Q K^T for 32 queries (2 m-subtiles); K fragments shared across m
        f32x4 sacc[2][4];
        for (int nt = 0; nt < 4; ++nt) {
            float mb = sbias[nt * 16 + q];
            sacc[0][nt] = f32x4{mb, mb, mb, mb};
            sacc[1][nt] = f32x4{mb, mb, mb, mb};
        }
        for (int dk = 0; dk < 2; ++dk) {
            for (int nt = 0; nt < 4; ++nt) {
                bf16x8 b = *(const bf16x8*)&Ks[nt * 16 + q][dk * 32 + 8 * h];
                sacc[0][nt] = MFMA(qf[0][dk], b, sacc[0][nt]);
                sacc[1][nt] = MFMA(qf[1][dk], b, sacc[1][nt]);
            }
        }
        // p = exp2(s); masked cols have s = -1e38 -> p = 0
        for (int m = 0; m < 2; ++m)
            for (int nt = 0; nt < 4; ++nt) {
                int kc = nt * 16 + q;
                for (int jj = 0; jj < 4; ++jj) {
                    float p = exp2f(sacc[m][nt][jj]);
                    Ps[w * 32 + m * 16 + 4 * h + jj][kc] = __float2bfloat16(p);
                }
            }
        __syncthreads();   // full LDS fence: order Ps stores before punned reads

        // acc += P @ V ; lsum += P @ ones; V fragments shared across m
        for (int kk = 0; kk < 2; ++kk) {
            bf16x8 ap0 = *(const bf16x8*)&Ps[w * 32 + q][kk * 32 + 8 * h];
            bf16x8 ap1 = *(const bf16x8*)&Ps[w * 32 + 16 + q][kk * 32 + 8 * h];
            lsum[0] = MFMA(ap0, ones, lsum[0]);
            lsum[1] = MFMA(ap1, ones, lsum[1]);
            for (int dt = 0; dt < 4; ++dt) {
                bf16x8 bv = *(const bf16x8*)&VTs[dt * 16 + q][kk * 32 + 8 * h];
                acc[0][dt] = MFMA(ap0, bv, acc[0][dt]);
                acc[1][dt] = MFMA(ap1, bv, acc[1][dt]);
            }
        }
    }

    // lane's lsum[m][jj] IS the row-sum for acc row jj of subtile m
    for (int m = 0; m < 2; ++m) {
        float rinv[4];
        for (int jj = 0; jj < 4; ++jj) rinv[jj] = 1.f / lsum[m][jj];
        const int ibase = qt * 128 + w * 32 + m * 16 + 4 * h;
        for (int dt = 0; dt < 4; ++dt) {
            int d = dt * 16 + q;
            union { __hip_bfloat16 hh[4]; uint2 u; } o;
            for (int jj = 0; jj < 4; ++jj)
                o.hh[jj] = __float2bfloat16(acc[m][dt][jj] * rinv[jj]);
            *(uint2*)(wvt + (size_t)g * (HD * SEQ) + (size_t)d * SEQ + ibase) = o.u;
        }
    }
}

// ---------------------------------------------------------------------------
// ws layout (26 MB peak): Xb [0,8MB) -> aliased by wvt after QKV GEMM;
// W bf16 [8,10MB); qb [10,18MB); kb [18,26MB).
// vT lives in d_out's first 8 MB (dead before gemm_out overwrites d_out).
// ---------------------------------------------------------------------------
extern "C" void kernel_launch(void* const* d_in, const int* in_sizes, int n_in,
                              void* d_out, int out_size, void* d_ws, size_t ws_size,
                              hipStream_t stream) {
    const float* lstm = (const float*)d_in[0];
    const int* mask = (const int*)d_in[1];
    const float* Wq = (const float*)d_in[2]; const float* bq = (const float*)d_in[3];
    const float* Wk = (const float*)d_in[4]; const float* bk = (const float*)d_in[5];
    const float* Wv = (const float*)d_in[6]; const float* bv = (const float*)d_in[7];
    const float* Wo = (const float*)d_in[8]; const float* bo = (const float*)d_in[9];
    float* out = (float*)d_out;

    const size_t NX = (size_t)MROWS * HID;    // 4M elems
    const size_t NW = (size_t)HID * HID;      // 256K elems
    __hip_bfloat16* Xb  = (__hip_bfloat16*)d_ws;            // 4M elems (8MB)
    __hip_bfloat16* Wqb = Xb + NX;                          // 256K
    __hip_bfloat16* Wkb = Wqb + NW;
    __hip_bfloat16* Wvb = Wkb + NW;
    __hip_bfloat16* Wob = Wvb + NW;
    __hip_bfloat16* qb  = Wob + NW;                         // 4M
    __hip_bfloat16* kb  = qb + NX;                          // 4M
    __hip_bfloat16* vT  = (__hip_bfloat16*)d_out;           // scratch in d_out[0,8MB)
    __hip_bfloat16* wvt = Xb;                               // alias: Xb dead after QKV GEMM

    conv_x<<<2048, 256, 0, stream>>>(lstm, Xb, (int)(NX / 4));
    conv_w<<<dim3(256, 4), 256, 0, stream>>>(Wq, Wk, Wv, Wo, Wqb);

    dim3 gg(MROWS / 64, HID / 64), bb(256);
    gemm_qkv_fused<<<gg, bb, 0, stream>>>(Xb, Wqb, Wkb, Wvb, bq, bk, bv, qb, kb, vT);
    attn<<<dim3(NG * (SEQ / 128)), bb, 0, stream>>>(qb, kb, vT, mask, wvt);
    gemm_out<<<gg, bb, 0, stream>>>(wvt, Wob, bo, out);
}

// Round 12
// 129.056 us; speedup vs baseline: 1.9226x; 1.1466x over previous
//
#include <hip/hip_runtime.h>
#include <hip/hip_bf16.h>

// Problem constants
#define HID 512
#define SEQ 2048
#define NG 32            // (B*NUM_HEADS) after the faithful-to-source flat reshape
#define HD 64
#define MROWS 8192       // B*SEQ
#define LDP 72           // padded LDS row stride (elems) = 144B
// 1/sqrt(512) * log2(e): folded into Q so softmax is exp2(s)
#define QSC 0.0637587178f

typedef __bf16 bf16x8 __attribute__((ext_vector_type(8)));
typedef float f32x4 __attribute__((ext_vector_type(4)));

#define MFMA(a, b, c) __builtin_amdgcn_mfma_f32_16x16x32_bf16((a), (b), (c), 0, 0, 0)

// ---------------------------------------------------------------------------
// prep: f32 -> bf16 vectorized converts
// ---------------------------------------------------------------------------
__global__ __launch_bounds__(256) void conv_x(const float* __restrict__ src,
                                              __hip_bfloat16* __restrict__ dst, int n4) {
    int stride = gridDim.x * 256;
    for (int i = blockIdx.x * 256 + threadIdx.x; i < n4; i += stride) {
        float4 v = *(const float4*)(src + (size_t)i * 4);
        union { __hip_bfloat16 h[4]; uint2 u; } p;
        p.h[0] = __float2bfloat16(v.x); p.h[1] = __float2bfloat16(v.y);
        p.h[2] = __float2bfloat16(v.z); p.h[3] = __float2bfloat16(v.w);
        *(uint2*)(dst + (size_t)i * 4) = p.u;
    }
}

__global__ __launch_bounds__(256) void conv_w(const float* __restrict__ a,
                                              const float* __restrict__ b,
                                              const float* __restrict__ c,
                                              const float* __restrict__ d,
                                              __hip_bfloat16* __restrict__ out) {
    int which = blockIdx.y;
    const float* s = which == 0 ? a : (which == 1 ? b : (which == 2 ? c : d));
    __hip_bfloat16* o = out + (size_t)which * (HID * HID);
    int i = blockIdx.x * 256 + threadIdx.x;   // 65536 float4 per W
    float4 v = *(const float4*)(s + (size_t)i * 4);
    union { __hip_bfloat16 h[4]; uint2 u; } p;
    p.h[0] = __float2bfloat16(v.x); p.h[1] = __float2bfloat16(v.y);
    p.h[2] = __float2bfloat16(v.z); p.h[3] = __float2bfloat16(v.w);
    *(uint2*)(o + (size_t)i * 4) = p.u;
}

// ---------------------------------------------------------------------------
// Fused QKV GEMM with T14 register prefetch across the stage barrier.
// q pre-scaled by QSC; v written transposed per head: vT[g][d][i].
// ---------------------------------------------------------------------------
__global__ __launch_bounds__(256) void gemm_qkv_fused(
        const __hip_bfloat16* __restrict__ Xb,
        const __hip_bfloat16* __restrict__ Wqb, const __hip_bfloat16* __restrict__ Wkb,
        const __hip_bfloat16* __restrict__ Wvb,
        const float* __restrict__ bq, const float* __restrict__ bk, const float* __restrict__ bv,
        __hip_bfloat16* __restrict__ qout, __hip_bfloat16* __restrict__ kout,
        __hip_bfloat16* __restrict__ vT) {
    __shared__ __hip_bfloat16 Xs[64][LDP];
    __shared__ __hip_bfloat16 Wqs[64][LDP];
    __shared__ __hip_bfloat16 Wks[64][LDP];
    __shared__ __hip_bfloat16 Wvs[64][LDP];
    const int tid = threadIdx.x;
    const int w = tid >> 6, l = tid & 63;
    const int row0 = blockIdx.x * 64, col0 = blockIdx.y * 64;

    const int r0 = tid >> 3, r1 = (tid + 256) >> 3;
    const int cc0 = (tid & 7) * 8;
    uint4 px0, px1, pq0, pq1, pk0, pk1, pv0, pv1;
    {
        px0 = *(const uint4*)(Xb  + (size_t)(row0 + r0) * HID + cc0);
        px1 = *(const uint4*)(Xb  + (size_t)(row0 + r1) * HID + cc0);
        pq0 = *(const uint4*)(Wqb + (size_t)(col0 + r0) * HID + cc0);
        pq1 = *(const uint4*)(Wqb + (size_t)(col0 + r1) * HID + cc0);
        pk0 = *(const uint4*)(Wkb + (size_t)(col0 + r0) * HID + cc0);
        pk1 = *(const uint4*)(Wkb + (size_t)(col0 + r1) * HID + cc0);
        pv0 = *(const uint4*)(Wvb + (size_t)(col0 + r0) * HID + cc0);
        pv1 = *(const uint4*)(Wvb + (size_t)(col0 + r1) * HID + cc0);
    }

    f32x4 aq[4] = {}, ak[4] = {}, av[4] = {};
    for (int kt = 0; kt < 8; ++kt) {
        __syncthreads();
        *(uint4*)&Xs[r0][cc0]  = px0;  *(uint4*)&Xs[r1][cc0]  = px1;
        *(uint4*)&Wqs[r0][cc0] = pq0;  *(uint4*)&Wqs[r1][cc0] = pq1;
        *(uint4*)&Wks[r0][cc0] = pk0;  *(uint4*)&Wks[r1][cc0] = pk1;
        *(uint4*)&Wvs[r0][cc0] = pv0;  *(uint4*)&Wvs[r1][cc0] = pv1;
        __syncthreads();
        if (kt < 7) {
            size_t go = (size_t)(kt + 1) * 64 + cc0;
            px0 = *(const uint4*)(Xb  + (size_t)(row0 + r0) * HID + go);
            px1 = *(const uint4*)(Xb  + (size_t)(row0 + r1) * HID + go);
            pq0 = *(const uint4*)(Wqb + (size_t)(col0 + r0) * HID + go);
            pq1 = *(const uint4*)(Wqb + (size_t)(col0 + r1) * HID + go);
            pk0 = *(const uint4*)(Wkb + (size_t)(col0 + r0) * HID + go);
            pk1 = *(const uint4*)(Wkb + (size_t)(col0 + r1) * HID + go);
            pv0 = *(const uint4*)(Wvb + (size_t)(col0 + r0) * HID + go);
            pv1 = *(const uint4*)(Wvb + (size_t)(col0 + r1) * HID + go);
        }
        for (int dk = 0; dk < 2; ++dk) {
            bf16x8 a = *(const bf16x8*)&Xs[w * 16 + (l & 15)][dk * 32 + 8 * (l >> 4)];
            for (int nt = 0; nt < 4; ++nt) {
                int rr = nt * 16 + (l & 15), cc = dk * 32 + 8 * (l >> 4);
                aq[nt] = MFMA(a, *(const bf16x8*)&Wqs[rr][cc], aq[nt]);
                ak[nt] = MFMA(a, *(const bf16x8*)&Wks[rr][cc], ak[nt]);
                av[nt] = MFMA(a, *(const bf16x8*)&Wvs[rr][cc], av[nt]);
            }
        }
    }
    // epilogue
    const int g = row0 >> 8;
    const int rbase = (row0 & 255) + w * 16 + 4 * (l >> 4);
    for (int nt = 0; nt < 4; ++nt) {
        int n = col0 + nt * 16 + (l & 15);
        float bqv = bq[n], bkv = bk[n], bvv = bv[n];
        int d = n & 63;   // col0 is a multiple of 64
        for (int jj = 0; jj < 4; ++jj) {
            int r = row0 + w * 16 + 4 * (l >> 4) + jj;
            qout[(size_t)r * HID + n] = __float2bfloat16((aq[nt][jj] + bqv) * QSC);
            kout[(size_t)r * HID + n] = __float2bfloat16(ak[nt][jj] + bkv);
            vT[(size_t)g * (HD * SEQ) + (size_t)d * SEQ + (rbase + jj) * 8 + blockIdx.y] =
                __float2bfloat16(av[nt][jj] + bvv);
        }
    }
}

// ---------------------------------------------------------------------------
// GEMM: out_f32[M x 512] = X_bf16 @ Wo_bf16^T + bo, with T14 reg prefetch.
// ---------------------------------------------------------------------------
__global__ __launch_bounds__(256) void gemm_out(const __hip_bfloat16* __restrict__ X,
                                                const __hip_bfloat16* __restrict__ W,
                                                const float* __restrict__ bias,
                                                float* __restrict__ out) {
    __shared__ __hip_bfloat16 Xs[64][LDP];
    __shared__ __hip_bfloat16 Ws[64][LDP];
    const int tid = threadIdx.x;
    const int w = tid >> 6, l = tid & 63;
    const int row0 = blockIdx.x * 64, col0 = blockIdx.y * 64;

    const int r0 = tid >> 3, r1 = (tid + 256) >> 3;
    const int cc0 = (tid & 7) * 8;
    uint4 px0 = *(const uint4*)(X + (size_t)(row0 + r0) * HID + cc0);
    uint4 px1 = *(const uint4*)(X + (size_t)(row0 + r1) * HID + cc0);
    uint4 pw0 = *(const uint4*)(W + (size_t)(col0 + r0) * HID + cc0);
    uint4 pw1 = *(const uint4*)(W + (size_t)(col0 + r1) * HID + cc0);

    f32x4 acc[4] = {};
    for (int kt = 0; kt < 8; ++kt) {
        __syncthreads();
        *(uint4*)&Xs[r0][cc0] = px0;  *(uint4*)&Xs[r1][cc0] = px1;
        *(uint4*)&Ws[r0][cc0] = pw0;  *(uint4*)&Ws[r1][cc0] = pw1;
        __syncthreads();
        if (kt < 7) {
            size_t go = (size_t)(kt + 1) * 64 + cc0;
            px0 = *(const uint4*)(X + (size_t)(row0 + r0) * HID + go);
            px1 = *(const uint4*)(X + (size_t)(row0 + r1) * HID + go);
            pw0 = *(const uint4*)(W + (size_t)(col0 + r0) * HID + go);
            pw1 = *(const uint4*)(W + (size_t)(col0 + r1) * HID + go);
        }
        for (int dk = 0; dk < 2; ++dk) {
            bf16x8 a = *(const bf16x8*)&Xs[w * 16 + (l & 15)][dk * 32 + 8 * (l >> 4)];
            for (int nt = 0; nt < 4; ++nt) {
                bf16x8 b = *(const bf16x8*)&Ws[nt * 16 + (l & 15)][dk * 32 + 8 * (l >> 4)];
                acc[nt] = MFMA(a, b, acc[nt]);
            }
        }
    }
    for (int nt = 0; nt < 4; ++nt) {
        int n = col0 + nt * 16 + (l & 15);
        float bv = bias[n];
        for (int jj = 0; jj < 4; ++jj) {
            int r = row0 + w * 16 + 4 * (l >> 4) + jj;
            out[(size_t)r * HID + n] = acc[nt][jj] + bv;
        }
    }
}

// ---------------------------------------------------------------------------
// Attention, swapped-QK^T in-register softmax. Compute S^T = MFMA(K, Q): lane
// (h, q=l&15) then holds P for query q at keys {16nt+4h+jj} — exactly the PV
// A-fragment it needs, given V staged with the column permutation
//   K_id(c) = 16*(c>>5) + 32*((c&7)>>2) + 4*((c>>3)&3) + (c&3).
// So P never touches LDS: no Ps array, no P stores/loads, no mid barrier.
// K/V/sbias double-buffered -> ONE barrier per k-tile. Mask bias enters as
// the S^T accumulator init (vector read of sbias, broadcast-free). Row-sums
// on the matrix pipe via all-ones MFMA, as verified in rounds 10-11.
// ---------------------------------------------------------------------------
__global__ __launch_bounds__(256) void attn(const __hip_bfloat16* __restrict__ qg,
                                            const __hip_bfloat16* __restrict__ kg,
                                            const __hip_bfloat16* __restrict__ vT,
                                            const int* __restrict__ mask,
                                            __hip_bfloat16* __restrict__ wvt) {
    __shared__ __hip_bfloat16 Ks[2][64][LDP];
    __shared__ __hip_bfloat16 VTs[2][64][LDP];
    __shared__ float sb[2][64];

    const int tid = threadIdx.x;
    const int w = tid >> 6, l = tid & 63;
    const int h = l >> 4, q = l & 15;
    // XCD-chunked swizzle: 512 blocks % 8 == 0 -> bijective
    const int bid = (blockIdx.x & 7) * 64 + (blockIdx.x >> 3);
    const int g = bid >> 4, qt = bid & 15;
    const size_t hb = (size_t)g * (SEQ * HD);

    // Q fragments in registers (one-time global read, L2-resident)
    bf16x8 qf[2][2];
    for (int m = 0; m < 2; ++m)
        for (int dk = 0; dk < 2; ++dk)
            qf[m][dk] = *(const bf16x8*)(qg + hb +
                (size_t)(qt * 128 + w * 32 + m * 16 + q) * HD + dk * 32 + 8 * h);

    const int r0 = tid >> 3, r1 = (tid + 256) >> 3;
    const int cc0 = (tid & 7) * 8;
    // permuted V dest base: keys cc0..cc0+3 -> cA..cA+3, cc0+4..+7 -> cA+8..+11
    const int ntc = cc0 >> 4;
    const int cA = (ntc & 1) * 32 + ((cc0 >> 2) & 3) * 8 + (ntc >> 1) * 4;

    const __bf16 kOne = (__bf16)1.0f;
    const bf16x8 ones = {kOne, kOne, kOne, kOne, kOne, kOne, kOne, kOne};

    f32x4 acc[2][4] = {};
    f32x4 lsum[2] = {};

    // ---- prologue: tile 0 into buf 0; tile 1 into regs ----
    uint4 kp0 = *(const uint4*)(kg + hb + (size_t)r0 * HD + cc0);
    uint4 kp1 = *(const uint4*)(kg + hb + (size_t)r1 * HD + cc0);
    uint4 vp0 = *(const uint4*)(vT + hb + (size_t)r0 * SEQ + cc0);
    uint4 vp1 = *(const uint4*)(vT + hb + (size_t)r1 * SEQ + cc0);
    int mpre = (tid < 64) ? mask[tid] : 0;

    *(uint4*)&Ks[0][r0][cc0] = kp0;
    *(uint4*)&Ks[0][r1][cc0] = kp1;
    *(uint2*)&VTs[0][r0][cA]     = make_uint2(vp0.x, vp0.y);
    *(uint2*)&VTs[0][r0][cA + 8] = make_uint2(vp0.z, vp0.w);
    *(uint2*)&VTs[0][r1][cA]     = make_uint2(vp1.x, vp1.y);
    *(uint2*)&VTs[0][r1][cA + 8] = make_uint2(vp1.z, vp1.w);
    if (tid < 64) sb[0][tid] = mpre ? 0.f : -1e38f;

    kp0 = *(const uint4*)(kg + hb + (size_t)(64 * HD) + (size_t)r0 * HD + cc0);
    kp1 = *(const uint4*)(kg + hb + (size_t)(64 * HD) + (size_t)r1 * HD + cc0);
    vp0 = *(const uint4*)(vT + hb + (size_t)r0 * SEQ + 64 + cc0);
    vp1 = *(const uint4*)(vT + hb + (size_t)r1 * SEQ + 64 + cc0);
    if (tid < 64) mpre = mask[64 + tid];
    __syncthreads();

    for (int kt = 0; kt < 32; ++kt) {
        const int cur = kt & 1;
        // stage next tile from regs into the other buffer (no conflict with
        // this iteration's reads of buf[cur]); then issue tile kt+2 loads
        if (kt < 31) {
            *(uint4*)&Ks[cur ^ 1][r0][cc0] = kp0;
            *(uint4*)&Ks[cur ^ 1][r1][cc0] = kp1;
            *(uint2*)&VTs[cur ^ 1][r0][cA]     = make_uint2(vp0.x, vp0.y);
            *(uint2*)&VTs[cur ^ 1][r0][cA + 8] = make_uint2(vp0.z, vp0.w);
            *(uint2*)&VTs[cur ^ 1][r1][cA]     = make_uint2(vp1.x, vp1.y);
            *(uint2*)&VTs[cur ^ 1][r1][cA + 8] = make_uint2(vp1.z, vp1.w);
            if (tid < 64) sb[cur ^ 1][tid] = mpre ? 0.f : -1e38f;
        }
        if (kt < 30) {
            const size_t ko = hb + (size_t)(kt + 2) * 64 * HD;
            kp0 = *(const uint4*)(kg + ko + (size_t)r0 * HD + cc0);
            kp1 = *(const uint4*)(kg + ko + (size_t)r1 * HD + cc0);
            vp0 = *(const uint4*)(vT + hb + (size_t)r0 * SEQ + (kt + 2) * 64 + cc0);
            vp1 = *(const uint4*)(vT + hb + (size_t)r1 * SEQ + (kt + 2) * 64 + cc0);
            if (tid < 64) mpre = mask[(kt + 2) * 64 + tid];
        }

        // S^T = K Q^T, accumulator init = per-key mask bias (vector read)
        f32x4 sacc[2][4];
        for (int nt = 0; nt < 4; ++nt) {
            f32x4 binit = *(const f32x4*)&sb[cur][nt * 16 + 4 * h];
            sacc[0][nt] = binit;
            sacc[1][nt] = binit;
        }
        for (int dk = 0; dk < 2; ++dk) {
            for (int nt = 0; nt < 4; ++nt) {
                bf16x8 kf = *(const bf16x8*)&Ks[cur][nt * 16 + q][dk * 32 + 8 * h];
                sacc[0][nt] = MFMA(kf, qf[0][dk], sacc[0][nt]);
                sacc[1][nt] = MFMA(kf, qf[1][dk], sacc[1][nt]);
            }
        }
        // p = exp2(s^T) packed straight into PV A-fragments (in registers):
        // pa[m][kk] = { sacc[m][kk][0..3], sacc[m][kk+2][0..3] }
        union pk_t { bf16x8 v; __hip_bfloat16 hh[8]; } pa[2][2];
        for (int m = 0; m < 2; ++m)
            for (int kk = 0; kk < 2; ++kk)
                for (int j = 0; j < 4; ++j) {
                    pa[m][kk].hh[j]     = __float2bfloat16(exp2f(sacc[m][kk][j]));
                    pa[m][kk].hh[j + 4] = __float2bfloat16(exp2f(sacc[m][kk + 2][j]));
                }
        // acc += P @ V ; lsum += P @ ones  (V columns permuted to match)
        for (int kk = 0; kk < 2; ++kk) {
            lsum[0] = MFMA(pa[0][kk].v, ones, lsum[0]);
            lsum[1] = MFMA(pa[1][kk].v, ones, lsum[1]);
            for (int dt = 0; dt < 4; ++dt) {
                bf16x8 bv = *(const bf16x8*)&VTs[cur][dt * 16 + q][kk * 32 + 8 * h];
                acc[0][dt] = MFMA(pa[0][kk].v, bv, acc[0][dt]);
                acc[1][dt] = MFMA(pa[1][kk].v, bv, acc[1][dt]);
            }
        }
        __syncthreads();   // writes to buf[cur^1] done; reads of buf[cur] done
    }

    // lane's lsum[m][jj] IS the row-sum for acc row jj of subtile m
    for (int m = 0; m < 2; ++m) {
        float rinv[4];
        for (int jj = 0; jj < 4; ++jj) rinv[jj] = 1.f / lsum[m][jj];
        const int ibase = qt * 128 + w * 32 + m * 16 + 4 * h;
        for (int dt = 0; dt < 4; ++dt) {
            int d = dt * 16 + q;
            union { __hip_bfloat16 hh[4]; uint2 u; } o;
            for (int jj = 0; jj < 4; ++jj)
                o.hh[jj] = __float2bfloat16(acc[m][dt][jj] * rinv[jj]);
            *(uint2*)(wvt + (size_t)g * (HD * SEQ) + (size_t)d * SEQ + ibase) = o.u;
        }
    }
}

// ---------------------------------------------------------------------------
// ws layout (26 MB peak): Xb [0,8MB) -> aliased by wvt after QKV GEMM;
// W bf16 [8,10MB); qb [10,18MB); kb [18,26MB).
// vT lives in d_out's first 8 MB (dead before gemm_out overwrites d_out).
// ---------------------------------------------------------------------------
extern "C" void kernel_launch(void* const* d_in, const int* in_sizes, int n_in,
                              void* d_out, int out_size, void* d_ws, size_t ws_size,
                              hipStream_t stream) {
    const float* lstm = (const float*)d_in[0];
    const int* mask = (const int*)d_in[1];
    const float* Wq = (const float*)d_in[2]; const float* bq = (const float*)d_in[3];
    const float* Wk = (const float*)d_in[4]; const float* bk = (const float*)d_in[5];
    const float* Wv = (const float*)d_in[6]; const float* bv = (const float*)d_in[7];
    const float* Wo = (const float*)d_in[8]; const float* bo = (const float*)d_in[9];
    float* out = (float*)d_out;

    const size_t NX = (size_t)MROWS * HID;    // 4M elems
    const size_t NW = (size_t)HID * HID;      // 256K elems
    __hip_bfloat16* Xb  = (__hip_bfloat16*)d_ws;            // 4M elems (8MB)
    __hip_bfloat16* Wqb = Xb + NX;                          // 256K
    __hip_bfloat16* Wkb = Wqb + NW;
    __hip_bfloat16* Wvb = Wkb + NW;
    __hip_bfloat16* Wob = Wvb + NW;
    __hip_bfloat16* qb  = Wob + NW;                         // 4M
    __hip_bfloat16* kb  = qb + NX;                          // 4M
    __hip_bfloat16* vT  = (__hip_bfloat16*)d_out;           // scratch in d_out[0,8MB)
    __hip_bfloat16* wvt = Xb;                               // alias: Xb dead after QKV GEMM

    conv_x<<<2048, 256, 0, stream>>>(lstm, Xb, (int)(NX / 4));
    conv_w<<<dim3(256, 4), 256, 0, stream>>>(Wq, Wk, Wv, Wo, Wqb);

    dim3 gg(MROWS / 64, HID / 64), bb(256);
    gemm_qkv_fused<<<gg, bb, 0, stream>>>(Xb, Wqb, Wkb, Wvb, bq, bk, bv, qb, kb, vT);
    attn<<<dim3(NG * (SEQ / 128)), bb, 0, stream>>>(qb, kb, vT, mask, wvt);
    gemm_out<<<gg, bb, 0, stream>>>(wvt, Wob, bo, out);
}